// Round 4
// baseline (383.560 us; speedup 1.0000x reference)
//
#include <hip/hip_runtime.h>
#include <hip/hip_cooperative_groups.h>

namespace cg = cooperative_groups;

#define IN_DIM  65536
#define OUT_DIM 65536
#define BATCH   256

// ws layout: float4 coeffs[OUT_DIM] @256 ; uint x_Tb[IN_DIM * BATCH/2] @2MiB (packed bf16 pairs).

__device__ __forceinline__ float bf2f(unsigned short h) {
    return __uint_as_float(((unsigned int)h) << 16);
}
__device__ __forceinline__ unsigned short f2bf(float f) {
    unsigned int u = __float_as_uint(f);
    u += 0x7FFFu + ((u >> 16) & 1u);
    return (unsigned short)(u >> 16);
}

// Softmax over 16 logits collapsed to affine coeffs of out = w0 + w1*a + w2*b + w3*ab.
__device__ __forceinline__ float4 collapse16(const float* w) {
    float m = w[0];
    #pragma unroll
    for (int f = 1; f < 16; ++f) m = fmaxf(m, w[f]);
    float e[16]; float sum = 0.f;
    #pragma unroll
    for (int f = 0; f < 16; ++f) { e[f] = __expf(w[f] - m); sum += e[f]; }
    float inv = 1.0f / sum;
    float w0 = e[8] + e[9] + e[10] + e[11] + e[12] + e[13] + e[14] + e[15];
    float w1 = (e[2] + e[3] + e[6] + e[7]) - (e[8] + e[9] + e[12] + e[13]);
    float w2 = (e[4] + e[5] + e[6] + e[7]) - (e[8] + e[9] + e[10] + e[11]);
    float w3 = e[1] - e[2] - e[4] - 2.f*e[6] - e[7]
             + e[8] + 2.f*e[9] + e[11] + e[13] - e[14];
    return make_float4(w0 * inv, w1 * inv, w2 * inv, w3 * inv);
}

#define TRANS_TILES ((IN_DIM / 64) * (BATCH / 64))   // 4096
#define LOGIC_TILES (OUT_DIM / 32)                   // 2048
#define TRANS_BLOCKS TRANS_TILES
#define COEFF_BLOCKS (OUT_DIM / 256)                 // 256
#define PAD 69   // 69 % 32 = 5 -> column-phase reads are <=2-way (free)

// ---------------------------------------------------------------------------
// Fused cooperative kernel (R7, resubmitted): phase 1 = transpose x ->
// packed-bf16 x_Tb + softmax-collapse coeffs; grid.sync(); phase 2 =
// row-staged gather + LDS-swizzled transpose + affine combine.
// Removes one kernel launch + gap, and makes the whole pipeline one
// dispatch (visible in rocprof top-k with its own counters).
// LDS: union of the 64x69 f32 transpose tile (17.6 KiB) and the 32 KiB
// swizzled row buffer -> 32 KiB -> 4 blocks/CU.
// ---------------------------------------------------------------------------
struct __align__(16) LdsU {
    union {
        float tile[64][PAD];     // phase 1
        uint4 rows4[64 * 32];    // phase 2 (32 KiB)
    };
};

__global__ __launch_bounds__(256, 4) void fused_kernel(
    const void* __restrict__ x_raw,       // [BATCH, IN_DIM] fp32 or bf16
    const void* __restrict__ w_raw,       // [OUT_DIM, 16]   fp32 or bf16
    const void* __restrict__ idx_raw,     // [2, OUT_DIM] int32 or int64
    unsigned int* __restrict__ x_Tb,      // [IN_DIM, BATCH/2] packed bf16
    float4* __restrict__ coeffs,          // [OUT_DIM]
    float* __restrict__ out)              // [BATCH, OUT_DIM]
{
    __shared__ LdsU u;
    __shared__ int sflag;
    int t  = threadIdx.x;
    int bx = blockIdx.x;
    int nb = gridDim.x;

    // ---- dtype probes (once per block; reads first 512B of each input) ----
    if (t == 0) sflag = 0;
    __syncthreads();
    {
        int fl = 0;
        if (((const unsigned short*)x_raw)[t] >= 0x3F80u) fl |= 1;
        if ((((const unsigned short*)w_raw)[t] & 0x7FFFu) >= 0x4800u) fl |= 2;
        if ((t & 1) && ((const int*)idx_raw)[t] != 0) fl |= 4;
        if (fl) atomicOr(&sflag, fl);
    }
    __syncthreads();
    const int x_is_f32   = sflag & 1;
    const int w_is_f32   = (sflag >> 1) & 1;
    const int idx_is_i32 = (sflag >> 2) & 1;

    // ---- phase 1a: coeffs (grid-stride over OUT_DIM) ----
    for (int o = bx * 256 + t; o < OUT_DIM; o += nb * 256) {
        float w[16];
        if (w_is_f32) {
            const float4* w4 = reinterpret_cast<const float4*>(w_raw) + (size_t)o * 4;
            float4 q0 = w4[0], q1 = w4[1], q2 = w4[2], q3 = w4[3];
            w[0]=q0.x; w[1]=q0.y; w[2]=q0.z; w[3]=q0.w;
            w[4]=q1.x; w[5]=q1.y; w[6]=q1.z; w[7]=q1.w;
            w[8]=q2.x; w[9]=q2.y; w[10]=q2.z; w[11]=q2.w;
            w[12]=q3.x; w[13]=q3.y; w[14]=q3.z; w[15]=q3.w;
        } else {
            const uint4* w16 = reinterpret_cast<const uint4*>(
                (const unsigned short*)w_raw + (size_t)o * 16);
            uint4 p0 = w16[0], p1 = w16[1];
            unsigned int pk[8] = { p0.x, p0.y, p0.z, p0.w, p1.x, p1.y, p1.z, p1.w };
            #pragma unroll
            for (int i = 0; i < 8; ++i) {
                w[2*i]   = bf2f((unsigned short)(pk[i] & 0xFFFFu));
                w[2*i+1] = bf2f((unsigned short)(pk[i] >> 16));
            }
        }
        coeffs[o] = collapse16(w);
    }

    // ---- phase 1b: transpose tiles (grid-stride over 4096 64x64 tiles) ----
    for (int tid = bx; tid < TRANS_TILES; tid += nb) {
        int c0 = (tid >> 2) * 64;   // input-dim tile
        int b0 = (tid & 3) * 64;    // batch tile
        int cq = t & 15;            // float4 col group
        int r  = t >> 4;            // 0..15

        __syncthreads();            // previous iteration's pack reads done
        if (x_is_f32) {
            const float4* x4 = (const float4*)x_raw;
            #pragma unroll
            for (int k = 0; k < 4; ++k) {
                int row = r + 16 * k;
                float4 v = x4[(size_t)(b0 + row) * (IN_DIM / 4) + (c0 >> 2) + cq];
                u.tile[row][4 * cq + 0] = v.x;
                u.tile[row][4 * cq + 1] = v.y;
                u.tile[row][4 * cq + 2] = v.z;
                u.tile[row][4 * cq + 3] = v.w;
            }
        } else {
            const uint2* x2 = (const uint2*)x_raw;  // 4 bf16 per uint2
            #pragma unroll
            for (int k = 0; k < 4; ++k) {
                int row = r + 16 * k;
                uint2 v = x2[(size_t)(b0 + row) * (IN_DIM / 4) + (c0 >> 2) + cq];
                u.tile[row][4 * cq + 0] = bf2f((unsigned short)(v.x & 0xFFFFu));
                u.tile[row][4 * cq + 1] = bf2f((unsigned short)(v.x >> 16));
                u.tile[row][4 * cq + 2] = bf2f((unsigned short)(v.y & 0xFFFFu));
                u.tile[row][4 * cq + 3] = bf2f((unsigned short)(v.y >> 16));
            }
        }
        __syncthreads();

        uint4* dst = (uint4*)x_Tb;
        int q   = t & 7;          // uint4 index within col (batch 8q..8q+7)
        int col = t >> 3;         // 0..31, second iter +32
        #pragma unroll
        for (int it = 0; it < 2; ++it) {
            int cc = col + 32 * it;
            unsigned int d[4];
            #pragma unroll
            for (int j = 0; j < 4; ++j) {
                float lo = u.tile[8 * q + 2 * j][cc];
                float hi = u.tile[8 * q + 2 * j + 1][cc];
                d[j] = (unsigned int)f2bf(lo) | ((unsigned int)f2bf(hi) << 16);
            }
            dst[(size_t)(c0 + cc) * (BATCH / 8) + (b0 >> 3) + q] =
                make_uint4(d[0], d[1], d[2], d[3]);
        }
    }

    // ---- grid-wide barrier: x_Tb + coeffs fully written & visible ----
    __threadfence();                 // release (device scope, cross-XCD)
    cg::this_grid().sync();
    __threadfence();                 // acquire

    // ---- phase 2: gather tiles (grid-stride over 2048 32-neuron tiles) ----
    const uint4* src4 = (const uint4*)x_Tb;
    for (int lt = bx; lt < LOGIC_TILES; lt += nb) {
        int o0 = lt * 32;
        int rr = t >> 5;          // 0..7: row within pass
        int l  = t & 31;          // uint4 slot within row

        int wires[8];
        if (idx_is_i32) {
            const int* p = (const int*)idx_raw;
            #pragma unroll
            for (int ps = 0; ps < 8; ++ps) {
                int r = rr + 8 * ps;
                wires[ps] = p[(r >> 5) * OUT_DIM + o0 + (r & 31)];
            }
        } else {
            const long long* p = (const long long*)idx_raw;
            #pragma unroll
            for (int ps = 0; ps < 8; ++ps) {
                int r = rr + 8 * ps;
                wires[ps] = (int)p[(r >> 5) * OUT_DIM + o0 + (r & 31)];
            }
        }

        __syncthreads();          // previous iteration's compute reads done
        #pragma unroll
        for (int ps = 0; ps < 8; ++ps) {
            int r = rr + 8 * ps;
            u.rows4[r * 32 + (l ^ (r & 31))] = src4[((size_t)wires[ps] << 5) + l];
        }
        float4 c = coeffs[o0 + (t & 31)];
        __syncthreads();

        int o = t & 31;           // neuron within tile (== swizzle key)
        const uint4* ra4 = u.rows4 + o * 32;
        const uint4* rb4 = u.rows4 + (32 + o) * 32;
        float* outp = out + o0 + o;
        #pragma unroll
        for (int i = 0; i < 4; ++i) {
            int bq = (t >> 5) + 8 * i;   // batch quad 0..31
            uint4 ua = ra4[bq ^ o];
            uint4 ub = rb4[bq ^ o];
            unsigned int pa[4] = { ua.x, ua.y, ua.z, ua.w };
            unsigned int pb[4] = { ub.x, ub.y, ub.z, ub.w };
            int base = bq * 8;
            #pragma unroll
            for (int j = 0; j < 4; ++j) {
                float a0 = bf2f((unsigned short)(pa[j] & 0xFFFFu));
                float a1 = bf2f((unsigned short)(pa[j] >> 16));
                float v0 = bf2f((unsigned short)(pb[j] & 0xFFFFu));
                float v1 = bf2f((unsigned short)(pb[j] >> 16));
                float r0v = fmaf(v0, fmaf(c.w, a0, c.z), fmaf(c.y, a0, c.x));
                float r1v = fmaf(v1, fmaf(c.w, a1, c.z), fmaf(c.y, a1, c.x));
                __builtin_nontemporal_store(r0v, outp + (size_t)(base + 2*j)     * OUT_DIM);
                __builtin_nontemporal_store(r1v, outp + (size_t)(base + 2*j + 1) * OUT_DIM);
            }
        }
    }
}

// ---------------------------------------------------------------------------
// Fallback pair (classic two-kernel path, proven at 139 us) — used if the
// cooperative launch is rejected (capture restriction / residency).
// ---------------------------------------------------------------------------
__global__ __launch_bounds__(256) void prep_kernel(
    const void* __restrict__ x_raw,
    const void* __restrict__ w_raw,
    unsigned int* __restrict__ x_Tb,
    float4* __restrict__ coeffs,
    int trans_blocks)
{
    __shared__ float tile[64][PAD];
    __shared__ int sflag;
    int t  = threadIdx.x;
    int bx = blockIdx.x;

    if (bx < trans_blocks) {
        if (t == 0) sflag = 0;
        __syncthreads();
        if (((const unsigned short*)x_raw)[t] >= 0x3F80u) atomicOr(&sflag, 1);
        __syncthreads();
        int x_is_f32 = sflag;

        int c0 = (bx >> 2) * 64;
        int b0 = (bx & 3) * 64;
        int cq = t & 15;
        int r  = t >> 4;

        if (x_is_f32) {
            const float4* x4 = (const float4*)x_raw;
            #pragma unroll
            for (int k = 0; k < 4; ++k) {
                int row = r + 16 * k;
                float4 v = x4[(size_t)(b0 + row) * (IN_DIM / 4) + (c0 >> 2) + cq];
                tile[row][4 * cq + 0] = v.x;
                tile[row][4 * cq + 1] = v.y;
                tile[row][4 * cq + 2] = v.z;
                tile[row][4 * cq + 3] = v.w;
            }
        } else {
            const uint2* x2 = (const uint2*)x_raw;
            #pragma unroll
            for (int k = 0; k < 4; ++k) {
                int row = r + 16 * k;
                uint2 v = x2[(size_t)(b0 + row) * (IN_DIM / 4) + (c0 >> 2) + cq];
                tile[row][4 * cq + 0] = bf2f((unsigned short)(v.x & 0xFFFFu));
                tile[row][4 * cq + 1] = bf2f((unsigned short)(v.x >> 16));
                tile[row][4 * cq + 2] = bf2f((unsigned short)(v.y & 0xFFFFu));
                tile[row][4 * cq + 3] = bf2f((unsigned short)(v.y >> 16));
            }
        }
        __syncthreads();

        uint4* dst = (uint4*)x_Tb;
        int q   = t & 7;
        int col = t >> 3;
        #pragma unroll
        for (int it = 0; it < 2; ++it) {
            int cc = col + 32 * it;
            unsigned int d[4];
            #pragma unroll
            for (int j = 0; j < 4; ++j) {
                float lo = tile[8 * q + 2 * j][cc];
                float hi = tile[8 * q + 2 * j + 1][cc];
                d[j] = (unsigned int)f2bf(lo) | ((unsigned int)f2bf(hi) << 16);
            }
            dst[(size_t)(c0 + cc) * (BATCH / 8) + (b0 >> 3) + q] =
                make_uint4(d[0], d[1], d[2], d[3]);
        }
    } else {
        if (t == 0) sflag = 0;
        __syncthreads();
        if ((((const unsigned short*)w_raw)[t] & 0x7FFFu) >= 0x4800u) atomicOr(&sflag, 1);
        __syncthreads();
        int w_is_f32 = sflag;

        int o = (bx - trans_blocks) * 256 + t;
        if (o >= OUT_DIM) return;

        float w[16];
        if (w_is_f32) {
            const float4* w4 = reinterpret_cast<const float4*>(w_raw) + (size_t)o * 4;
            float4 q0 = w4[0], q1 = w4[1], q2 = w4[2], q3 = w4[3];
            w[0]=q0.x; w[1]=q0.y; w[2]=q0.z; w[3]=q0.w;
            w[4]=q1.x; w[5]=q1.y; w[6]=q1.z; w[7]=q1.w;
            w[8]=q2.x; w[9]=q2.y; w[10]=q2.z; w[11]=q2.w;
            w[12]=q3.x; w[13]=q3.y; w[14]=q3.z; w[15]=q3.w;
        } else {
            const uint4* w16 = reinterpret_cast<const uint4*>(
                (const unsigned short*)w_raw + (size_t)o * 16);
            uint4 p0 = w16[0], p1 = w16[1];
            unsigned int pk[8] = { p0.x, p0.y, p0.z, p0.w, p1.x, p1.y, p1.z, p1.w };
            #pragma unroll
            for (int i = 0; i < 8; ++i) {
                w[2*i]   = bf2f((unsigned short)(pk[i] & 0xFFFFu));
                w[2*i+1] = bf2f((unsigned short)(pk[i] >> 16));
            }
        }
        coeffs[o] = collapse16(w);
    }
}

__global__ __launch_bounds__(256) void logic_bt_kernel(
    const unsigned int* __restrict__ x_Tb,
    const void* __restrict__ idx_raw,
    const float4* __restrict__ coeffs,
    float* __restrict__ out)
{
    __shared__ uint4 rows4[64 * 32];
    __shared__ int sflag;
    int t = threadIdx.x;
    if (t == 0) sflag = 0;
    __syncthreads();
    if ((t & 1) && ((const int*)idx_raw)[t] != 0) atomicOr(&sflag, 1);
    __syncthreads();
    int idx_is_i32 = sflag;

    int o0 = blockIdx.x * 32;
    int rr = t >> 5;
    int l  = t & 31;
    int wires[8];
    if (idx_is_i32) {
        const int* p = (const int*)idx_raw;
        #pragma unroll
        for (int ps = 0; ps < 8; ++ps) {
            int r = rr + 8 * ps;
            wires[ps] = p[(r >> 5) * OUT_DIM + o0 + (r & 31)];
        }
    } else {
        const long long* p = (const long long*)idx_raw;
        #pragma unroll
        for (int ps = 0; ps < 8; ++ps) {
            int r = rr + 8 * ps;
            wires[ps] = (int)p[(r >> 5) * OUT_DIM + o0 + (r & 31)];
        }
    }

    const uint4* src4 = (const uint4*)x_Tb;
    #pragma unroll
    for (int ps = 0; ps < 8; ++ps) {
        int r = rr + 8 * ps;
        rows4[r * 32 + (l ^ (r & 31))] = src4[((size_t)wires[ps] << 5) + l];
    }
    float4 c = coeffs[o0 + (t & 31)];
    __syncthreads();

    int o = t & 31;
    const uint4* ra4 = rows4 + o * 32;
    const uint4* rb4 = rows4 + (32 + o) * 32;
    float* outp = out + o0 + o;
    #pragma unroll
    for (int i = 0; i < 4; ++i) {
        int bq = (t >> 5) + 8 * i;
        uint4 ua = ra4[bq ^ o];
        uint4 ub = rb4[bq ^ o];
        unsigned int pa[4] = { ua.x, ua.y, ua.z, ua.w };
        unsigned int pb[4] = { ub.x, ub.y, ub.z, ub.w };
        int base = bq * 8;
        #pragma unroll
        for (int j = 0; j < 4; ++j) {
            float a0 = bf2f((unsigned short)(pa[j] & 0xFFFFu));
            float a1 = bf2f((unsigned short)(pa[j] >> 16));
            float v0 = bf2f((unsigned short)(pb[j] & 0xFFFFu));
            float v1 = bf2f((unsigned short)(pb[j] >> 16));
            float r0v = fmaf(v0, fmaf(c.w, a0, c.z), fmaf(c.y, a0, c.x));
            float r1v = fmaf(v1, fmaf(c.w, a1, c.z), fmaf(c.y, a1, c.x));
            __builtin_nontemporal_store(r0v, outp + (size_t)(base + 2*j)     * OUT_DIM);
            __builtin_nontemporal_store(r1v, outp + (size_t)(base + 2*j + 1) * OUT_DIM);
        }
    }
}

__global__ __launch_bounds__(256) void logic_direct_kernel(
    const void* __restrict__ x_raw,
    const void* __restrict__ idx_raw,
    const float4* __restrict__ coeffs,
    float* __restrict__ out)
{
    __shared__ int sflag;
    int t = threadIdx.x;
    if (t == 0) sflag = 0;
    __syncthreads();
    int fl = 0;
    if (((const unsigned short*)x_raw)[t] >= 0x3F80u) fl |= 1;
    if ((t & 1) && ((const int*)idx_raw)[t] != 0) fl |= 2;
    if (fl) atomicOr(&sflag, fl);
    __syncthreads();
    int x_is_f32   = sflag & 1;
    int idx_is_i32 = (sflag >> 1) & 1;

    int o = blockIdx.x * 256 + t;
    int ia, ib;
    if (idx_is_i32) {
        const int* p = (const int*)idx_raw;
        ia = p[o];       ib = p[OUT_DIM + o];
    } else {
        const long long* p = (const long long*)idx_raw;
        ia = (int)p[o];  ib = (int)p[OUT_DIM + o];
    }
    float4 c = coeffs[o];
    int b0 = blockIdx.y * 32;

    if (x_is_f32) {
        const float* xa = (const float*)x_raw + ia;
        const float* xb = (const float*)x_raw + ib;
        #pragma unroll 8
        for (int r = 0; r < 32; ++r) {
            int b = b0 + r;
            float av = xa[(size_t)b * IN_DIM];
            float bv = xb[(size_t)b * IN_DIM];
            out[(size_t)b * OUT_DIM + o] =
                fmaf(bv, fmaf(c.w, av, c.z), fmaf(c.y, av, c.x));
        }
    } else {
        const unsigned short* xa = (const unsigned short*)x_raw + ia;
        const unsigned short* xb = (const unsigned short*)x_raw + ib;
        #pragma unroll 8
        for (int r = 0; r < 32; ++r) {
            int b = b0 + r;
            float av = bf2f(xa[(size_t)b * IN_DIM]);
            float bv = bf2f(xb[(size_t)b * IN_DIM]);
            out[(size_t)b * OUT_DIM + o] =
                fmaf(bv, fmaf(c.w, av, c.z), fmaf(c.y, av, c.x));
        }
    }
}

extern "C" void kernel_launch(void* const* d_in, const int* in_sizes, int n_in,
                              void* d_out, int out_size, void* d_ws, size_t ws_size,
                              hipStream_t stream) {
    const void* x       = d_in[0];
    const void* weights = d_in[1];
    const void* indices = d_in[2];
    float*      out     = (float*)d_out;

    float4*       coeffs = (float4*)((char*)d_ws + 256);
    unsigned int* x_Tb   = (unsigned int*)((char*)d_ws + 2u * 1024u * 1024u);

    const size_t need = 2u * 1024u * 1024u +
                        (size_t)IN_DIM * (BATCH / 2) * sizeof(unsigned int); // ~34 MiB

    if (ws_size >= need) {
        // grid sized for guaranteed co-residency (cooperative requirement)
        static int s_nb = 0;
        if (s_nb == 0) {
            int maxPerCU = 0;
            if (hipOccupancyMaxActiveBlocksPerMultiprocessor(
                    &maxPerCU, reinterpret_cast<const void*>(fused_kernel),
                    256, 0) != hipSuccess || maxPerCU < 1) {
                maxPerCU = 2;  // conservative floor
            }
            long nb = (long)maxPerCU * 256;   // 256 CUs on MI355X
            if (nb > 1024) nb = 1024;
            s_nb = (int)nb;
        }

        void* args[] = { (void*)&x, (void*)&weights, (void*)&indices,
                         (void*)&x_Tb, (void*)&coeffs, (void*)&out };
        hipError_t err = hipLaunchCooperativeKernel(
            reinterpret_cast<const void*>(fused_kernel),
            dim3(s_nb), dim3(256), args, 0, stream);

        if (err != hipSuccess) {
            (void)hipGetLastError();   // clear, fall back to classic path
            prep_kernel<<<dim3(TRANS_BLOCKS + COEFF_BLOCKS), dim3(256), 0, stream>>>(
                x, weights, x_Tb, coeffs, TRANS_BLOCKS);
            logic_bt_kernel<<<dim3(OUT_DIM / 32), dim3(256), 0, stream>>>(
                x_Tb, indices, coeffs, out);
        }
    } else {
        prep_kernel<<<dim3(COEFF_BLOCKS), dim3(256), 0, stream>>>(
            x, weights, x_Tb, coeffs, /*trans_blocks=*/0);
        dim3 grid(OUT_DIM / 256, BATCH / 32);
        logic_direct_kernel<<<grid, dim3(256), 0, stream>>>(
            x, indices, coeffs, out);
    }
}

// Round 6
// 353.480 us; speedup vs baseline: 1.0851x; 1.0851x over previous
//
#include <hip/hip_runtime.h>

#define IN_DIM  65536
#define OUT_DIM 65536
#define BATCH   256

// ws layout: float4 coeffs[OUT_DIM] @256 ; uint x_Tb[IN_DIM * BATCH/2] @2MiB (packed bf16 pairs).

__device__ __forceinline__ float bf2f(unsigned short h) {
    return __uint_as_float(((unsigned int)h) << 16);
}
__device__ __forceinline__ unsigned short f2bf(float f) {
    unsigned int u = __float_as_uint(f);
    u += 0x7FFFu + ((u >> 16) & 1u);
    return (unsigned short)(u >> 16);
}

// Softmax over 16 logits collapsed to affine coeffs of out = w0 + w1*a + w2*b + w3*ab.
__device__ __forceinline__ float4 collapse16(const float* w) {
    float m = w[0];
    #pragma unroll
    for (int f = 1; f < 16; ++f) m = fmaxf(m, w[f]);
    float e[16]; float sum = 0.f;
    #pragma unroll
    for (int f = 0; f < 16; ++f) { e[f] = __expf(w[f] - m); sum += e[f]; }
    float inv = 1.0f / sum;
    float w0 = e[8] + e[9] + e[10] + e[11] + e[12] + e[13] + e[14] + e[15];
    float w1 = (e[2] + e[3] + e[6] + e[7]) - (e[8] + e[9] + e[12] + e[13]);
    float w2 = (e[4] + e[5] + e[6] + e[7]) - (e[8] + e[9] + e[10] + e[11]);
    float w3 = e[1] - e[2] - e[4] - 2.f*e[6] - e[7]
             + e[8] + 2.f*e[9] + e[11] + e[13] - e[14];
    return make_float4(w0 * inv, w1 * inv, w2 * inv, w3 * inv);
}

#define TRANS_TILES ((IN_DIM / 64) * (BATCH / 64))   // 4096
#define HALF_TILES  ((OUT_DIM / 32) * 2)             // 4096 (32 neurons x 128-batch halves)
#define TRANS_BLOCKS TRANS_TILES
#define COEFF_BLOCKS (OUT_DIM / 256)                 // 256
#define PAD 69   // 69 % 32 = 5 -> column-phase reads are <=2-way (free)

// ---------------------------------------------------------------------------
// R8 (resubmitted): fused kernel with CUSTOM sleep-based grid barrier.
// R4 post-mortem: cg::this_grid().sync() spin (device-scope polling on one
// line from 1024 WGs) throttled the fabric -> 345 us @ 490 GB/s, VALU 2.2%.
// Fixes: (1) sense-reversing barrier in __device__ globals, pollers back off
// with s_sleep(32) (~2K cycles/poll) -> negligible poll traffic;
// (2) LDS halved to 17.7 KB (phase-2 tile = 32 neurons x 128-batch half,
// 256B rows; same 64 MB total gather, same full-line 128B output stores)
// -> 8 blocks/CU (was 4).
// ---------------------------------------------------------------------------
__device__ unsigned int g_bar_count = 0;
__device__ unsigned int g_bar_gen   = 0;

__device__ __forceinline__ void grid_sleep_barrier(int nb) {
    __syncthreads();
    if (threadIdx.x == 0) {
        __threadfence();   // release: this block's global writes visible device-wide
        unsigned int gen = __hip_atomic_load(&g_bar_gen, __ATOMIC_ACQUIRE,
                                             __HIP_MEMORY_SCOPE_AGENT);
        unsigned int old = __hip_atomic_fetch_add(&g_bar_count, 1u, __ATOMIC_ACQ_REL,
                                                  __HIP_MEMORY_SCOPE_AGENT);
        if (old == (unsigned int)nb - 1u) {
            __hip_atomic_store(&g_bar_count, 0u, __ATOMIC_RELAXED,
                               __HIP_MEMORY_SCOPE_AGENT);
            __hip_atomic_store(&g_bar_gen, gen + 1u, __ATOMIC_RELEASE,
                               __HIP_MEMORY_SCOPE_AGENT);
        } else {
            while (__hip_atomic_load(&g_bar_gen, __ATOMIC_ACQUIRE,
                                     __HIP_MEMORY_SCOPE_AGENT) == gen) {
                __builtin_amdgcn_s_sleep(32);   // ~2048 cy between polls
            }
        }
        __threadfence();   // acquire: see all blocks' writes
    }
    __syncthreads();
}

struct __align__(16) LdsU {
    union {
        float tile[64][PAD];     // phase 1: 17664 B
        uint4 rows4[64 * 16];    // phase 2: 16384 B (64 rows x 256B half-rows)
    };
};

__global__ __launch_bounds__(256, 8) void fused_kernel(
    const void* __restrict__ x_raw,       // [BATCH, IN_DIM] fp32 or bf16
    const void* __restrict__ w_raw,       // [OUT_DIM, 16]   fp32 or bf16
    const void* __restrict__ idx_raw,     // [2, OUT_DIM] int32 or int64
    unsigned int* __restrict__ x_Tb,      // [IN_DIM, BATCH/2] packed bf16
    float4* __restrict__ coeffs,          // [OUT_DIM]
    float* __restrict__ out,              // [BATCH, OUT_DIM]
    int nb)
{
    __shared__ LdsU u;
    __shared__ int sflag;
    int t  = threadIdx.x;
    int bx = blockIdx.x;

    // ---- dtype probes (once per block; reads first 512B of each input) ----
    if (t == 0) sflag = 0;
    __syncthreads();
    {
        int fl = 0;
        if (((const unsigned short*)x_raw)[t] >= 0x3F80u) fl |= 1;
        if ((((const unsigned short*)w_raw)[t] & 0x7FFFu) >= 0x4800u) fl |= 2;
        if ((t & 1) && ((const int*)idx_raw)[t] != 0) fl |= 4;
        if (fl) atomicOr(&sflag, fl);
    }
    __syncthreads();
    const int x_is_f32   = sflag & 1;
    const int w_is_f32   = (sflag >> 1) & 1;
    const int idx_is_i32 = (sflag >> 2) & 1;

    // ---- phase 1a: coeffs (grid-stride over OUT_DIM) ----
    for (int o = bx * 256 + t; o < OUT_DIM; o += nb * 256) {
        float w[16];
        if (w_is_f32) {
            const float4* w4 = reinterpret_cast<const float4*>(w_raw) + (size_t)o * 4;
            float4 q0 = w4[0], q1 = w4[1], q2 = w4[2], q3 = w4[3];
            w[0]=q0.x; w[1]=q0.y; w[2]=q0.z; w[3]=q0.w;
            w[4]=q1.x; w[5]=q1.y; w[6]=q1.z; w[7]=q1.w;
            w[8]=q2.x; w[9]=q2.y; w[10]=q2.z; w[11]=q2.w;
            w[12]=q3.x; w[13]=q3.y; w[14]=q3.z; w[15]=q3.w;
        } else {
            const uint4* w16 = reinterpret_cast<const uint4*>(
                (const unsigned short*)w_raw + (size_t)o * 16);
            uint4 p0 = w16[0], p1 = w16[1];
            unsigned int pk[8] = { p0.x, p0.y, p0.z, p0.w, p1.x, p1.y, p1.z, p1.w };
            #pragma unroll
            for (int i = 0; i < 8; ++i) {
                w[2*i]   = bf2f((unsigned short)(pk[i] & 0xFFFFu));
                w[2*i+1] = bf2f((unsigned short)(pk[i] >> 16));
            }
        }
        coeffs[o] = collapse16(w);
    }

    // ---- phase 1b: transpose tiles (grid-stride over 4096 64x64 tiles) ----
    for (int tid = bx; tid < TRANS_TILES; tid += nb) {
        int c0 = (tid >> 2) * 64;   // input-dim tile
        int b0 = (tid & 3) * 64;    // batch tile
        int cq = t & 15;            // float4 col group
        int r  = t >> 4;            // 0..15

        __syncthreads();            // previous iteration's pack reads done
        if (x_is_f32) {
            const float4* x4 = (const float4*)x_raw;
            #pragma unroll
            for (int k = 0; k < 4; ++k) {
                int row = r + 16 * k;
                float4 v = x4[(size_t)(b0 + row) * (IN_DIM / 4) + (c0 >> 2) + cq];
                u.tile[row][4 * cq + 0] = v.x;
                u.tile[row][4 * cq + 1] = v.y;
                u.tile[row][4 * cq + 2] = v.z;
                u.tile[row][4 * cq + 3] = v.w;
            }
        } else {
            const uint2* x2 = (const uint2*)x_raw;  // 4 bf16 per uint2
            #pragma unroll
            for (int k = 0; k < 4; ++k) {
                int row = r + 16 * k;
                uint2 v = x2[(size_t)(b0 + row) * (IN_DIM / 4) + (c0 >> 2) + cq];
                u.tile[row][4 * cq + 0] = bf2f((unsigned short)(v.x & 0xFFFFu));
                u.tile[row][4 * cq + 1] = bf2f((unsigned short)(v.x >> 16));
                u.tile[row][4 * cq + 2] = bf2f((unsigned short)(v.y & 0xFFFFu));
                u.tile[row][4 * cq + 3] = bf2f((unsigned short)(v.y >> 16));
            }
        }
        __syncthreads();

        uint4* dst = (uint4*)x_Tb;
        int q   = t & 7;          // uint4 index within col (batch 8q..8q+7)
        int col = t >> 3;         // 0..31, second iter +32
        #pragma unroll
        for (int it = 0; it < 2; ++it) {
            int cc = col + 32 * it;
            unsigned int d[4];
            #pragma unroll
            for (int j = 0; j < 4; ++j) {
                float lo = u.tile[8 * q + 2 * j][cc];
                float hi = u.tile[8 * q + 2 * j + 1][cc];
                d[j] = (unsigned int)f2bf(lo) | ((unsigned int)f2bf(hi) << 16);
            }
            dst[(size_t)(c0 + cc) * (BATCH / 8) + (b0 >> 3) + q] =
                make_uint4(d[0], d[1], d[2], d[3]);
        }
    }

    // ---- grid-wide barrier: x_Tb + coeffs fully written & visible ----
    grid_sleep_barrier(nb);

    // ---- phase 2: gather tiles (grid-stride over 4096 half-batch tiles) ----
    // tile lt: neurons o0..o0+31 (o0 = (lt>>1)*32), batch half h = lt&1.
    // 64 rows x 256B (16 uint4) staged, XOR-swizzled l ^ (r&15).
    const uint4* src4 = (const uint4*)x_Tb;
    for (int lt = bx; lt < HALF_TILES; lt += nb) {
        int o0 = (lt >> 1) * 32;
        int hc = (lt & 1) * 16;   // uint4 col offset within full row
        int rr = t >> 4;          // 0..15: row within pass
        int l  = t & 15;          // uint4 slot within 256B half-row

        int wires[4];
        if (idx_is_i32) {
            const int* p = (const int*)idx_raw;
            #pragma unroll
            for (int ps = 0; ps < 4; ++ps) {
                int r = rr + 16 * ps;                // 0..63
                wires[ps] = p[(r >> 5) * OUT_DIM + o0 + (r & 31)];
            }
        } else {
            const long long* p = (const long long*)idx_raw;
            #pragma unroll
            for (int ps = 0; ps < 4; ++ps) {
                int r = rr + 16 * ps;
                wires[ps] = (int)p[(r >> 5) * OUT_DIM + o0 + (r & 31)];
            }
        }

        __syncthreads();          // previous iteration's compute reads done
        #pragma unroll
        for (int ps = 0; ps < 4; ++ps) {
            int r = rr + 16 * ps;
            u.rows4[r * 16 + (l ^ (r & 15))] =
                src4[(size_t)wires[ps] * (BATCH / 8) + hc + l];
        }
        float4 c = coeffs[o0 + (t & 31)];
        __syncthreads();

        int o = t & 31;           // neuron within tile
        const uint4* ra4 = u.rows4 + o * 16;
        const uint4* rb4 = u.rows4 + (32 + o) * 16;
        float* outp = out + o0 + o;
        int B0 = (lt & 1) * 128;
        #pragma unroll
        for (int i = 0; i < 2; ++i) {
            int bq = (t >> 5) + 8 * i;      // batch quad within half: 0..15
            uint4 ua = ra4[bq ^ (o & 15)];
            uint4 ub = rb4[bq ^ (o & 15)];
            unsigned int pa[4] = { ua.x, ua.y, ua.z, ua.w };
            unsigned int pb[4] = { ub.x, ub.y, ub.z, ub.w };
            int base = B0 + bq * 8;
            #pragma unroll
            for (int j = 0; j < 4; ++j) {
                float a0 = bf2f((unsigned short)(pa[j] & 0xFFFFu));
                float a1 = bf2f((unsigned short)(pa[j] >> 16));
                float v0 = bf2f((unsigned short)(pb[j] & 0xFFFFu));
                float v1 = bf2f((unsigned short)(pb[j] >> 16));
                float r0v = fmaf(v0, fmaf(c.w, a0, c.z), fmaf(c.y, a0, c.x));
                float r1v = fmaf(v1, fmaf(c.w, a1, c.z), fmaf(c.y, a1, c.x));
                __builtin_nontemporal_store(r0v, outp + (size_t)(base + 2*j)     * OUT_DIM);
                __builtin_nontemporal_store(r1v, outp + (size_t)(base + 2*j + 1) * OUT_DIM);
            }
        }
    }
}

// ---------------------------------------------------------------------------
// Fallback pair (classic two-kernel path, proven at 139 us) — used if the
// cooperative launch is rejected.
// ---------------------------------------------------------------------------
__global__ __launch_bounds__(256) void prep_kernel(
    const void* __restrict__ x_raw,
    const void* __restrict__ w_raw,
    unsigned int* __restrict__ x_Tb,
    float4* __restrict__ coeffs,
    int trans_blocks)
{
    __shared__ float tile[64][PAD];
    __shared__ int sflag;
    int t  = threadIdx.x;
    int bx = blockIdx.x;

    if (bx < trans_blocks) {
        if (t == 0) sflag = 0;
        __syncthreads();
        if (((const unsigned short*)x_raw)[t] >= 0x3F80u) atomicOr(&sflag, 1);
        __syncthreads();
        int x_is_f32 = sflag;

        int c0 = (bx >> 2) * 64;
        int b0 = (bx & 3) * 64;
        int cq = t & 15;
        int r  = t >> 4;

        if (x_is_f32) {
            const float4* x4 = (const float4*)x_raw;
            #pragma unroll
            for (int k = 0; k < 4; ++k) {
                int row = r + 16 * k;
                float4 v = x4[(size_t)(b0 + row) * (IN_DIM / 4) + (c0 >> 2) + cq];
                tile[row][4 * cq + 0] = v.x;
                tile[row][4 * cq + 1] = v.y;
                tile[row][4 * cq + 2] = v.z;
                tile[row][4 * cq + 3] = v.w;
            }
        } else {
            const uint2* x2 = (const uint2*)x_raw;
            #pragma unroll
            for (int k = 0; k < 4; ++k) {
                int row = r + 16 * k;
                uint2 v = x2[(size_t)(b0 + row) * (IN_DIM / 4) + (c0 >> 2) + cq];
                tile[row][4 * cq + 0] = bf2f((unsigned short)(v.x & 0xFFFFu));
                tile[row][4 * cq + 1] = bf2f((unsigned short)(v.x >> 16));
                tile[row][4 * cq + 2] = bf2f((unsigned short)(v.y & 0xFFFFu));
                tile[row][4 * cq + 3] = bf2f((unsigned short)(v.y >> 16));
            }
        }
        __syncthreads();

        uint4* dst = (uint4*)x_Tb;
        int q   = t & 7;
        int col = t >> 3;
        #pragma unroll
        for (int it = 0; it < 2; ++it) {
            int cc = col + 32 * it;
            unsigned int d[4];
            #pragma unroll
            for (int j = 0; j < 4; ++j) {
                float lo = tile[8 * q + 2 * j][cc];
                float hi = tile[8 * q + 2 * j + 1][cc];
                d[j] = (unsigned int)f2bf(lo) | ((unsigned int)f2bf(hi) << 16);
            }
            dst[(size_t)(c0 + cc) * (BATCH / 8) + (b0 >> 3) + q] =
                make_uint4(d[0], d[1], d[2], d[3]);
        }
    } else {
        if (t == 0) sflag = 0;
        __syncthreads();
        if ((((const unsigned short*)w_raw)[t] & 0x7FFFu) >= 0x4800u) atomicOr(&sflag, 1);
        __syncthreads();
        int w_is_f32 = sflag;

        int o = (bx - trans_blocks) * 256 + t;
        if (o >= OUT_DIM) return;

        float w[16];
        if (w_is_f32) {
            const float4* w4 = reinterpret_cast<const float4*>(w_raw) + (size_t)o * 4;
            float4 q0 = w4[0], q1 = w4[1], q2 = w4[2], q3 = w4[3];
            w[0]=q0.x; w[1]=q0.y; w[2]=q0.z; w[3]=q0.w;
            w[4]=q1.x; w[5]=q1.y; w[6]=q1.z; w[7]=q1.w;
            w[8]=q2.x; w[9]=q2.y; w[10]=q2.z; w[11]=q2.w;
            w[12]=q3.x; w[13]=q3.y; w[14]=q3.z; w[15]=q3.w;
        } else {
            const uint4* w16 = reinterpret_cast<const uint4*>(
                (const unsigned short*)w_raw + (size_t)o * 16);
            uint4 p0 = w16[0], p1 = w16[1];
            unsigned int pk[8] = { p0.x, p0.y, p0.z, p0.w, p1.x, p1.y, p1.z, p1.w };
            #pragma unroll
            for (int i = 0; i < 8; ++i) {
                w[2*i]   = bf2f((unsigned short)(pk[i] & 0xFFFFu));
                w[2*i+1] = bf2f((unsigned short)(pk[i] >> 16));
            }
        }
        coeffs[o] = collapse16(w);
    }
}

__global__ __launch_bounds__(256) void logic_bt_kernel(
    const unsigned int* __restrict__ x_Tb,
    const void* __restrict__ idx_raw,
    const float4* __restrict__ coeffs,
    float* __restrict__ out)
{
    __shared__ uint4 rows4[64 * 32];
    __shared__ int sflag;
    int t = threadIdx.x;
    if (t == 0) sflag = 0;
    __syncthreads();
    if ((t & 1) && ((const int*)idx_raw)[t] != 0) atomicOr(&sflag, 1);
    __syncthreads();
    int idx_is_i32 = sflag;

    int o0 = blockIdx.x * 32;
    int rr = t >> 5;
    int l  = t & 31;
    int wires[8];
    if (idx_is_i32) {
        const int* p = (const int*)idx_raw;
        #pragma unroll
        for (int ps = 0; ps < 8; ++ps) {
            int r = rr + 8 * ps;
            wires[ps] = p[(r >> 5) * OUT_DIM + o0 + (r & 31)];
        }
    } else {
        const long long* p = (const long long*)idx_raw;
        #pragma unroll
        for (int ps = 0; ps < 8; ++ps) {
            int r = rr + 8 * ps;
            wires[ps] = (int)p[(r >> 5) * OUT_DIM + o0 + (r & 31)];
        }
    }

    const uint4* src4 = (const uint4*)x_Tb;
    #pragma unroll
    for (int ps = 0; ps < 8; ++ps) {
        int r = rr + 8 * ps;
        rows4[r * 32 + (l ^ (r & 31))] = src4[((size_t)wires[ps] << 5) + l];
    }
    float4 c = coeffs[o0 + (t & 31)];
    __syncthreads();

    int o = t & 31;
    const uint4* ra4 = rows4 + o * 32;
    const uint4* rb4 = rows4 + (32 + o) * 32;
    float* outp = out + o0 + o;
    #pragma unroll
    for (int i = 0; i < 4; ++i) {
        int bq = (t >> 5) + 8 * i;
        uint4 ua = ra4[bq ^ o];
        uint4 ub = rb4[bq ^ o];
        unsigned int pa[4] = { ua.x, ua.y, ua.z, ua.w };
        unsigned int pb[4] = { ub.x, ub.y, ub.z, ub.w };
        int base = bq * 8;
        #pragma unroll
        for (int j = 0; j < 4; ++j) {
            float a0 = bf2f((unsigned short)(pa[j] & 0xFFFFu));
            float a1 = bf2f((unsigned short)(pa[j] >> 16));
            float v0 = bf2f((unsigned short)(pb[j] & 0xFFFFu));
            float v1 = bf2f((unsigned short)(pb[j] >> 16));
            float r0v = fmaf(v0, fmaf(c.w, a0, c.z), fmaf(c.y, a0, c.x));
            float r1v = fmaf(v1, fmaf(c.w, a1, c.z), fmaf(c.y, a1, c.x));
            __builtin_nontemporal_store(r0v, outp + (size_t)(base + 2*j)     * OUT_DIM);
            __builtin_nontemporal_store(r1v, outp + (size_t)(base + 2*j + 1) * OUT_DIM);
        }
    }
}

__global__ __launch_bounds__(256) void logic_direct_kernel(
    const void* __restrict__ x_raw,
    const void* __restrict__ idx_raw,
    const float4* __restrict__ coeffs,
    float* __restrict__ out)
{
    __shared__ int sflag;
    int t = threadIdx.x;
    if (t == 0) sflag = 0;
    __syncthreads();
    int fl = 0;
    if (((const unsigned short*)x_raw)[t] >= 0x3F80u) fl |= 1;
    if ((t & 1) && ((const int*)idx_raw)[t] != 0) fl |= 2;
    if (fl) atomicOr(&sflag, fl);
    __syncthreads();
    int x_is_f32   = sflag & 1;
    int idx_is_i32 = (sflag >> 1) & 1;

    int o = blockIdx.x * 256 + t;
    int ia, ib;
    if (idx_is_i32) {
        const int* p = (const int*)idx_raw;
        ia = p[o];       ib = p[OUT_DIM + o];
    } else {
        const long long* p = (const long long*)idx_raw;
        ia = (int)p[o];  ib = (int)p[OUT_DIM + o];
    }
    float4 c = coeffs[o];
    int b0 = blockIdx.y * 32;

    if (x_is_f32) {
        const float* xa = (const float*)x_raw + ia;
        const float* xb = (const float*)x_raw + ib;
        #pragma unroll 8
        for (int r = 0; r < 32; ++r) {
            int b = b0 + r;
            float av = xa[(size_t)b * IN_DIM];
            float bv = xb[(size_t)b * IN_DIM];
            out[(size_t)b * OUT_DIM + o] =
                fmaf(bv, fmaf(c.w, av, c.z), fmaf(c.y, av, c.x));
        }
    } else {
        const unsigned short* xa = (const unsigned short*)x_raw + ia;
        const unsigned short* xb = (const unsigned short*)x_raw + ib;
        #pragma unroll 8
        for (int r = 0; r < 32; ++r) {
            int b = b0 + r;
            float av = bf2f(xa[(size_t)b * IN_DIM]);
            float bv = bf2f(xb[(size_t)b * IN_DIM]);
            out[(size_t)b * OUT_DIM + o] =
                fmaf(bv, fmaf(c.w, av, c.z), fmaf(c.y, av, c.x));
        }
    }
}

extern "C" void kernel_launch(void* const* d_in, const int* in_sizes, int n_in,
                              void* d_out, int out_size, void* d_ws, size_t ws_size,
                              hipStream_t stream) {
    const void* x       = d_in[0];
    const void* weights = d_in[1];
    const void* indices = d_in[2];
    float*      out     = (float*)d_out;

    float4*       coeffs = (float4*)((char*)d_ws + 256);
    unsigned int* x_Tb   = (unsigned int*)((char*)d_ws + 2u * 1024u * 1024u);

    const size_t need = 2u * 1024u * 1024u +
                        (size_t)IN_DIM * (BATCH / 2) * sizeof(unsigned int); // ~34 MiB

    if (ws_size >= need) {
        // grid sized for guaranteed co-residency (cooperative requirement)
        static int s_nb = 0;
        if (s_nb == 0) {
            int maxPerCU = 0;
            if (hipOccupancyMaxActiveBlocksPerMultiprocessor(
                    &maxPerCU, reinterpret_cast<const void*>(fused_kernel),
                    256, 0) != hipSuccess || maxPerCU < 1) {
                maxPerCU = 4;  // conservative floor
            }
            if (maxPerCU > 8) maxPerCU = 8;
            s_nb = maxPerCU * 256;   // 256 CUs on MI355X; <= 2048
        }
        int nb = s_nb;

        void* args[] = { (void*)&x, (void*)&weights, (void*)&indices,
                         (void*)&x_Tb, (void*)&coeffs, (void*)&out, (void*)&nb };
        hipError_t err = hipLaunchCooperativeKernel(
            reinterpret_cast<const void*>(fused_kernel),
            dim3(nb), dim3(256), args, 0, stream);

        if (err != hipSuccess) {
            (void)hipGetLastError();   // clear, fall back to classic path
            prep_kernel<<<dim3(TRANS_BLOCKS + COEFF_BLOCKS), dim3(256), 0, stream>>>(
                x, weights, x_Tb, coeffs, TRANS_BLOCKS);
            logic_bt_kernel<<<dim3(OUT_DIM / 32), dim3(256), 0, stream>>>(
                x_Tb, indices, coeffs, out);
        }
    } else {
        prep_kernel<<<dim3(COEFF_BLOCKS), dim3(256), 0, stream>>>(
            x, weights, x_Tb, coeffs, /*trans_blocks=*/0);
        dim3 grid(OUT_DIM / 256, BATCH / 32);
        logic_direct_kernel<<<grid, dim3(256), 0, stream>>>(
            x, indices, coeffs, out);
    }
}

// Round 7
// 329.471 us; speedup vs baseline: 1.1642x; 1.0729x over previous
//
#include <hip/hip_runtime.h>

#define IN_DIM  65536
#define OUT_DIM 65536
#define BATCH   256

// ws layout: float4 coeffs[OUT_DIM] @256 ; uint x_Tb[IN_DIM * BATCH/2] @2MiB (packed bf16 pairs).

__device__ __forceinline__ float bf2f(unsigned short h) {
    return __uint_as_float(((unsigned int)h) << 16);
}
__device__ __forceinline__ unsigned short f2bf(float f) {
    unsigned int u = __float_as_uint(f);
    u += 0x7FFFu + ((u >> 16) & 1u);
    return (unsigned short)(u >> 16);
}

// Softmax over 16 logits collapsed to affine coeffs of out = w0 + w1*a + w2*b + w3*ab.
__device__ __forceinline__ float4 collapse16(const float* w) {
    float m = w[0];
    #pragma unroll
    for (int f = 1; f < 16; ++f) m = fmaxf(m, w[f]);
    float e[16]; float sum = 0.f;
    #pragma unroll
    for (int f = 0; f < 16; ++f) { e[f] = __expf(w[f] - m); sum += e[f]; }
    float inv = 1.0f / sum;
    float w0 = e[8] + e[9] + e[10] + e[11] + e[12] + e[13] + e[14] + e[15];
    float w1 = (e[2] + e[3] + e[6] + e[7]) - (e[8] + e[9] + e[12] + e[13]);
    float w2 = (e[4] + e[5] + e[6] + e[7]) - (e[8] + e[9] + e[10] + e[11]);
    float w3 = e[1] - e[2] - e[4] - 2.f*e[6] - e[7]
             + e[8] + 2.f*e[9] + e[11] + e[13] - e[14];
    return make_float4(w0 * inv, w1 * inv, w2 * inv, w3 * inv);
}

#define TRANS_TILES ((IN_DIM / 64) * (BATCH / 64))   // 4096
#define HALF_TILES  ((OUT_DIM / 32) * 2)             // 4096 (32 neurons x 128-batch halves)
#define TRANS_BLOCKS TRANS_TILES
#define COEFF_BLOCKS (OUT_DIM / 256)                 // 256
#define PAD 69   // 69 % 32 = 5 -> column-phase reads are <=2-way (free)

// ---------------------------------------------------------------------------
// R9: SAME fused kernel + sleep barrier as R6, but launched with a PLAIN
// <<<>>> launch (single-variable A/B vs R6's hipLaunchCooperativeKernel).
// R6 post-mortem: sleep barrier + 95% occupancy did NOT fix the ~98% stall
// (450 us, VALU 1.9% < a memset's 4.2%) -> stall is uniform across the
// kernel and independent of barrier mechanism => suspect the cooperative
// dispatch path itself. The custom barrier only needs co-residency:
// grid = 1024 (4 blocks/CU) vs true capacity 8/CU (28 VGPR, 17.9KB LDS)
// gives 2x residency slack on an exclusive stream. Phases divide evenly
// (4096/1024 = 4 iterations each).
// ---------------------------------------------------------------------------
__device__ unsigned int g_bar_count = 0;
__device__ unsigned int g_bar_gen   = 0;

__device__ __forceinline__ void grid_sleep_barrier(int nb) {
    __syncthreads();
    if (threadIdx.x == 0) {
        __threadfence();   // release: this block's global writes visible device-wide
        unsigned int gen = __hip_atomic_load(&g_bar_gen, __ATOMIC_ACQUIRE,
                                             __HIP_MEMORY_SCOPE_AGENT);
        unsigned int old = __hip_atomic_fetch_add(&g_bar_count, 1u, __ATOMIC_ACQ_REL,
                                                  __HIP_MEMORY_SCOPE_AGENT);
        if (old == (unsigned int)nb - 1u) {
            __hip_atomic_store(&g_bar_count, 0u, __ATOMIC_RELAXED,
                               __HIP_MEMORY_SCOPE_AGENT);
            __hip_atomic_store(&g_bar_gen, gen + 1u, __ATOMIC_RELEASE,
                               __HIP_MEMORY_SCOPE_AGENT);
        } else {
            while (__hip_atomic_load(&g_bar_gen, __ATOMIC_ACQUIRE,
                                     __HIP_MEMORY_SCOPE_AGENT) == gen) {
                __builtin_amdgcn_s_sleep(32);   // ~2048 cy between polls
            }
        }
        __threadfence();   // acquire: see all blocks' writes
    }
    __syncthreads();
}

struct __align__(16) LdsU {
    union {
        float tile[64][PAD];     // phase 1: 17664 B
        uint4 rows4[64 * 16];    // phase 2: 16384 B (64 rows x 256B half-rows)
    };
};

__global__ __launch_bounds__(256, 8) void fused_kernel(
    const void* __restrict__ x_raw,       // [BATCH, IN_DIM] fp32 or bf16
    const void* __restrict__ w_raw,       // [OUT_DIM, 16]   fp32 or bf16
    const void* __restrict__ idx_raw,     // [2, OUT_DIM] int32 or int64
    unsigned int* __restrict__ x_Tb,      // [IN_DIM, BATCH/2] packed bf16
    float4* __restrict__ coeffs,          // [OUT_DIM]
    float* __restrict__ out,              // [BATCH, OUT_DIM]
    int nb)
{
    __shared__ LdsU u;
    __shared__ int sflag;
    int t  = threadIdx.x;
    int bx = blockIdx.x;

    // ---- dtype probes (once per block; reads first 512B of each input) ----
    if (t == 0) sflag = 0;
    __syncthreads();
    {
        int fl = 0;
        if (((const unsigned short*)x_raw)[t] >= 0x3F80u) fl |= 1;
        if ((((const unsigned short*)w_raw)[t] & 0x7FFFu) >= 0x4800u) fl |= 2;
        if ((t & 1) && ((const int*)idx_raw)[t] != 0) fl |= 4;
        if (fl) atomicOr(&sflag, fl);
    }
    __syncthreads();
    const int x_is_f32   = sflag & 1;
    const int w_is_f32   = (sflag >> 1) & 1;
    const int idx_is_i32 = (sflag >> 2) & 1;

    // ---- phase 1a: coeffs (grid-stride over OUT_DIM) ----
    for (int o = bx * 256 + t; o < OUT_DIM; o += nb * 256) {
        float w[16];
        if (w_is_f32) {
            const float4* w4 = reinterpret_cast<const float4*>(w_raw) + (size_t)o * 4;
            float4 q0 = w4[0], q1 = w4[1], q2 = w4[2], q3 = w4[3];
            w[0]=q0.x; w[1]=q0.y; w[2]=q0.z; w[3]=q0.w;
            w[4]=q1.x; w[5]=q1.y; w[6]=q1.z; w[7]=q1.w;
            w[8]=q2.x; w[9]=q2.y; w[10]=q2.z; w[11]=q2.w;
            w[12]=q3.x; w[13]=q3.y; w[14]=q3.z; w[15]=q3.w;
        } else {
            const uint4* w16 = reinterpret_cast<const uint4*>(
                (const unsigned short*)w_raw + (size_t)o * 16);
            uint4 p0 = w16[0], p1 = w16[1];
            unsigned int pk[8] = { p0.x, p0.y, p0.z, p0.w, p1.x, p1.y, p1.z, p1.w };
            #pragma unroll
            for (int i = 0; i < 8; ++i) {
                w[2*i]   = bf2f((unsigned short)(pk[i] & 0xFFFFu));
                w[2*i+1] = bf2f((unsigned short)(pk[i] >> 16));
            }
        }
        coeffs[o] = collapse16(w);
    }

    // ---- phase 1b: transpose tiles (grid-stride over 4096 64x64 tiles) ----
    for (int tid = bx; tid < TRANS_TILES; tid += nb) {
        int c0 = (tid >> 2) * 64;   // input-dim tile
        int b0 = (tid & 3) * 64;    // batch tile
        int cq = t & 15;            // float4 col group
        int r  = t >> 4;            // 0..15

        __syncthreads();            // previous iteration's pack reads done
        if (x_is_f32) {
            const float4* x4 = (const float4*)x_raw;
            #pragma unroll
            for (int k = 0; k < 4; ++k) {
                int row = r + 16 * k;
                float4 v = x4[(size_t)(b0 + row) * (IN_DIM / 4) + (c0 >> 2) + cq];
                u.tile[row][4 * cq + 0] = v.x;
                u.tile[row][4 * cq + 1] = v.y;
                u.tile[row][4 * cq + 2] = v.z;
                u.tile[row][4 * cq + 3] = v.w;
            }
        } else {
            const uint2* x2 = (const uint2*)x_raw;  // 4 bf16 per uint2
            #pragma unroll
            for (int k = 0; k < 4; ++k) {
                int row = r + 16 * k;
                uint2 v = x2[(size_t)(b0 + row) * (IN_DIM / 4) + (c0 >> 2) + cq];
                u.tile[row][4 * cq + 0] = bf2f((unsigned short)(v.x & 0xFFFFu));
                u.tile[row][4 * cq + 1] = bf2f((unsigned short)(v.x >> 16));
                u.tile[row][4 * cq + 2] = bf2f((unsigned short)(v.y & 0xFFFFu));
                u.tile[row][4 * cq + 3] = bf2f((unsigned short)(v.y >> 16));
            }
        }
        __syncthreads();

        uint4* dst = (uint4*)x_Tb;
        int q   = t & 7;          // uint4 index within col (batch 8q..8q+7)
        int col = t >> 3;         // 0..31, second iter +32
        #pragma unroll
        for (int it = 0; it < 2; ++it) {
            int cc = col + 32 * it;
            unsigned int d[4];
            #pragma unroll
            for (int j = 0; j < 4; ++j) {
                float lo = u.tile[8 * q + 2 * j][cc];
                float hi = u.tile[8 * q + 2 * j + 1][cc];
                d[j] = (unsigned int)f2bf(lo) | ((unsigned int)f2bf(hi) << 16);
            }
            dst[(size_t)(c0 + cc) * (BATCH / 8) + (b0 >> 3) + q] =
                make_uint4(d[0], d[1], d[2], d[3]);
        }
    }

    // ---- grid-wide barrier: x_Tb + coeffs fully written & visible ----
    grid_sleep_barrier(nb);

    // ---- phase 2: gather tiles (grid-stride over 4096 half-batch tiles) ----
    // tile lt: neurons o0..o0+31 (o0 = (lt>>1)*32), batch half h = lt&1.
    // 64 rows x 256B (16 uint4) staged, XOR-swizzled l ^ (r&15).
    const uint4* src4 = (const uint4*)x_Tb;
    for (int lt = bx; lt < HALF_TILES; lt += nb) {
        int o0 = (lt >> 1) * 32;
        int hc = (lt & 1) * 16;   // uint4 col offset within full row
        int rr = t >> 4;          // 0..15: row within pass
        int l  = t & 15;          // uint4 slot within 256B half-row

        int wires[4];
        if (idx_is_i32) {
            const int* p = (const int*)idx_raw;
            #pragma unroll
            for (int ps = 0; ps < 4; ++ps) {
                int r = rr + 16 * ps;                // 0..63
                wires[ps] = p[(r >> 5) * OUT_DIM + o0 + (r & 31)];
            }
        } else {
            const long long* p = (const long long*)idx_raw;
            #pragma unroll
            for (int ps = 0; ps < 4; ++ps) {
                int r = rr + 16 * ps;
                wires[ps] = (int)p[(r >> 5) * OUT_DIM + o0 + (r & 31)];
            }
        }

        __syncthreads();          // previous iteration's compute reads done
        #pragma unroll
        for (int ps = 0; ps < 4; ++ps) {
            int r = rr + 16 * ps;
            u.rows4[r * 16 + (l ^ (r & 15))] =
                src4[(size_t)wires[ps] * (BATCH / 8) + hc + l];
        }
        float4 c = coeffs[o0 + (t & 31)];
        __syncthreads();

        int o = t & 31;           // neuron within tile
        const uint4* ra4 = u.rows4 + o * 16;
        const uint4* rb4 = u.rows4 + (32 + o) * 16;
        float* outp = out + o0 + o;
        int B0 = (lt & 1) * 128;
        #pragma unroll
        for (int i = 0; i < 2; ++i) {
            int bq = (t >> 5) + 8 * i;      // batch quad within half: 0..15
            uint4 ua = ra4[bq ^ (o & 15)];
            uint4 ub = rb4[bq ^ (o & 15)];
            unsigned int pa[4] = { ua.x, ua.y, ua.z, ua.w };
            unsigned int pb[4] = { ub.x, ub.y, ub.z, ub.w };
            int base = B0 + bq * 8;
            #pragma unroll
            for (int j = 0; j < 4; ++j) {
                float a0 = bf2f((unsigned short)(pa[j] & 0xFFFFu));
                float a1 = bf2f((unsigned short)(pa[j] >> 16));
                float v0 = bf2f((unsigned short)(pb[j] & 0xFFFFu));
                float v1 = bf2f((unsigned short)(pb[j] >> 16));
                float r0v = fmaf(v0, fmaf(c.w, a0, c.z), fmaf(c.y, a0, c.x));
                float r1v = fmaf(v1, fmaf(c.w, a1, c.z), fmaf(c.y, a1, c.x));
                __builtin_nontemporal_store(r0v, outp + (size_t)(base + 2*j)     * OUT_DIM);
                __builtin_nontemporal_store(r1v, outp + (size_t)(base + 2*j + 1) * OUT_DIM);
            }
        }
    }
}

// ---------------------------------------------------------------------------
// Fallback pair (classic two-kernel path, proven at 139 us) — used if ws is
// too small for x_Tb.
// ---------------------------------------------------------------------------
__global__ __launch_bounds__(256) void prep_kernel(
    const void* __restrict__ x_raw,
    const void* __restrict__ w_raw,
    unsigned int* __restrict__ x_Tb,
    float4* __restrict__ coeffs,
    int trans_blocks)
{
    __shared__ float tile[64][PAD];
    __shared__ int sflag;
    int t  = threadIdx.x;
    int bx = blockIdx.x;

    if (bx < trans_blocks) {
        if (t == 0) sflag = 0;
        __syncthreads();
        if (((const unsigned short*)x_raw)[t] >= 0x3F80u) atomicOr(&sflag, 1);
        __syncthreads();
        int x_is_f32 = sflag;

        int c0 = (bx >> 2) * 64;
        int b0 = (bx & 3) * 64;
        int cq = t & 15;
        int r  = t >> 4;

        if (x_is_f32) {
            const float4* x4 = (const float4*)x_raw;
            #pragma unroll
            for (int k = 0; k < 4; ++k) {
                int row = r + 16 * k;
                float4 v = x4[(size_t)(b0 + row) * (IN_DIM / 4) + (c0 >> 2) + cq];
                tile[row][4 * cq + 0] = v.x;
                tile[row][4 * cq + 1] = v.y;
                tile[row][4 * cq + 2] = v.z;
                tile[row][4 * cq + 3] = v.w;
            }
        } else {
            const uint2* x2 = (const uint2*)x_raw;
            #pragma unroll
            for (int k = 0; k < 4; ++k) {
                int row = r + 16 * k;
                uint2 v = x2[(size_t)(b0 + row) * (IN_DIM / 4) + (c0 >> 2) + cq];
                tile[row][4 * cq + 0] = bf2f((unsigned short)(v.x & 0xFFFFu));
                tile[row][4 * cq + 1] = bf2f((unsigned short)(v.x >> 16));
                tile[row][4 * cq + 2] = bf2f((unsigned short)(v.y & 0xFFFFu));
                tile[row][4 * cq + 3] = bf2f((unsigned short)(v.y >> 16));
            }
        }
        __syncthreads();

        uint4* dst = (uint4*)x_Tb;
        int q   = t & 7;
        int col = t >> 3;
        #pragma unroll
        for (int it = 0; it < 2; ++it) {
            int cc = col + 32 * it;
            unsigned int d[4];
            #pragma unroll
            for (int j = 0; j < 4; ++j) {
                float lo = tile[8 * q + 2 * j][cc];
                float hi = tile[8 * q + 2 * j + 1][cc];
                d[j] = (unsigned int)f2bf(lo) | ((unsigned int)f2bf(hi) << 16);
            }
            dst[(size_t)(c0 + cc) * (BATCH / 8) + (b0 >> 3) + q] =
                make_uint4(d[0], d[1], d[2], d[3]);
        }
    } else {
        if (t == 0) sflag = 0;
        __syncthreads();
        if ((((const unsigned short*)w_raw)[t] & 0x7FFFu) >= 0x4800u) atomicOr(&sflag, 1);
        __syncthreads();
        int w_is_f32 = sflag;

        int o = (bx - trans_blocks) * 256 + t;
        if (o >= OUT_DIM) return;

        float w[16];
        if (w_is_f32) {
            const float4* w4 = reinterpret_cast<const float4*>(w_raw) + (size_t)o * 4;
            float4 q0 = w4[0], q1 = w4[1], q2 = w4[2], q3 = w4[3];
            w[0]=q0.x; w[1]=q0.y; w[2]=q0.z; w[3]=q0.w;
            w[4]=q1.x; w[5]=q1.y; w[6]=q1.z; w[7]=q1.w;
            w[8]=q2.x; w[9]=q2.y; w[10]=q2.z; w[11]=q2.w;
            w[12]=q3.x; w[13]=q3.y; w[14]=q3.z; w[15]=q3.w;
        } else {
            const uint4* w16 = reinterpret_cast<const uint4*>(
                (const unsigned short*)w_raw + (size_t)o * 16);
            uint4 p0 = w16[0], p1 = w16[1];
            unsigned int pk[8] = { p0.x, p0.y, p0.z, p0.w, p1.x, p1.y, p1.z, p1.w };
            #pragma unroll
            for (int i = 0; i < 8; ++i) {
                w[2*i]   = bf2f((unsigned short)(pk[i] & 0xFFFFu));
                w[2*i+1] = bf2f((unsigned short)(pk[i] >> 16));
            }
        }
        coeffs[o] = collapse16(w);
    }
}

__global__ __launch_bounds__(256) void logic_bt_kernel(
    const unsigned int* __restrict__ x_Tb,
    const void* __restrict__ idx_raw,
    const float4* __restrict__ coeffs,
    float* __restrict__ out)
{
    __shared__ uint4 rows4[64 * 32];
    __shared__ int sflag;
    int t = threadIdx.x;
    if (t == 0) sflag = 0;
    __syncthreads();
    if ((t & 1) && ((const int*)idx_raw)[t] != 0) atomicOr(&sflag, 1);
    __syncthreads();
    int idx_is_i32 = sflag;

    int o0 = blockIdx.x * 32;
    int rr = t >> 5;
    int l  = t & 31;
    int wires[8];
    if (idx_is_i32) {
        const int* p = (const int*)idx_raw;
        #pragma unroll
        for (int ps = 0; ps < 8; ++ps) {
            int r = rr + 8 * ps;
            wires[ps] = p[(r >> 5) * OUT_DIM + o0 + (r & 31)];
        }
    } else {
        const long long* p = (const long long*)idx_raw;
        #pragma unroll
        for (int ps = 0; ps < 8; ++ps) {
            int r = rr + 8 * ps;
            wires[ps] = (int)p[(r >> 5) * OUT_DIM + o0 + (r & 31)];
        }
    }

    const uint4* src4 = (const uint4*)x_Tb;
    #pragma unroll
    for (int ps = 0; ps < 8; ++ps) {
        int r = rr + 8 * ps;
        rows4[r * 32 + (l ^ (r & 31))] = src4[((size_t)wires[ps] << 5) + l];
    }
    float4 c = coeffs[o0 + (t & 31)];
    __syncthreads();

    int o = t & 31;
    const uint4* ra4 = rows4 + o * 32;
    const uint4* rb4 = rows4 + (32 + o) * 32;
    float* outp = out + o0 + o;
    #pragma unroll
    for (int i = 0; i < 4; ++i) {
        int bq = (t >> 5) + 8 * i;
        uint4 ua = ra4[bq ^ o];
        uint4 ub = rb4[bq ^ o];
        unsigned int pa[4] = { ua.x, ua.y, ua.z, ua.w };
        unsigned int pb[4] = { ub.x, ub.y, ub.z, ub.w };
        int base = bq * 8;
        #pragma unroll
        for (int j = 0; j < 4; ++j) {
            float a0 = bf2f((unsigned short)(pa[j] & 0xFFFFu));
            float a1 = bf2f((unsigned short)(pa[j] >> 16));
            float v0 = bf2f((unsigned short)(pb[j] & 0xFFFFu));
            float v1 = bf2f((unsigned short)(pb[j] >> 16));
            float r0v = fmaf(v0, fmaf(c.w, a0, c.z), fmaf(c.y, a0, c.x));
            float r1v = fmaf(v1, fmaf(c.w, a1, c.z), fmaf(c.y, a1, c.x));
            __builtin_nontemporal_store(r0v, outp + (size_t)(base + 2*j)     * OUT_DIM);
            __builtin_nontemporal_store(r1v, outp + (size_t)(base + 2*j + 1) * OUT_DIM);
        }
    }
}

__global__ __launch_bounds__(256) void logic_direct_kernel(
    const void* __restrict__ x_raw,
    const void* __restrict__ idx_raw,
    const float4* __restrict__ coeffs,
    float* __restrict__ out)
{
    __shared__ int sflag;
    int t = threadIdx.x;
    if (t == 0) sflag = 0;
    __syncthreads();
    int fl = 0;
    if (((const unsigned short*)x_raw)[t] >= 0x3F80u) fl |= 1;
    if ((t & 1) && ((const int*)idx_raw)[t] != 0) fl |= 2;
    if (fl) atomicOr(&sflag, fl);
    __syncthreads();
    int x_is_f32   = sflag & 1;
    int idx_is_i32 = (sflag >> 1) & 1;

    int o = blockIdx.x * 256 + t;
    int ia, ib;
    if (idx_is_i32) {
        const int* p = (const int*)idx_raw;
        ia = p[o];       ib = p[OUT_DIM + o];
    } else {
        const long long* p = (const long long*)idx_raw;
        ia = (int)p[o];  ib = (int)p[OUT_DIM + o];
    }
    float4 c = coeffs[o];
    int b0 = blockIdx.y * 32;

    if (x_is_f32) {
        const float* xa = (const float*)x_raw + ia;
        const float* xb = (const float*)x_raw + ib;
        #pragma unroll 8
        for (int r = 0; r < 32; ++r) {
            int b = b0 + r;
            float av = xa[(size_t)b * IN_DIM];
            float bv = xb[(size_t)b * IN_DIM];
            out[(size_t)b * OUT_DIM + o] =
                fmaf(bv, fmaf(c.w, av, c.z), fmaf(c.y, av, c.x));
        }
    } else {
        const unsigned short* xa = (const unsigned short*)x_raw + ia;
        const unsigned short* xb = (const unsigned short*)x_raw + ib;
        #pragma unroll 8
        for (int r = 0; r < 32; ++r) {
            int b = b0 + r;
            float av = bf2f(xa[(size_t)b * IN_DIM]);
            float bv = bf2f(xb[(size_t)b * IN_DIM]);
            out[(size_t)b * OUT_DIM + o] =
                fmaf(bv, fmaf(c.w, av, c.z), fmaf(c.y, av, c.x));
        }
    }
}

extern "C" void kernel_launch(void* const* d_in, const int* in_sizes, int n_in,
                              void* d_out, int out_size, void* d_ws, size_t ws_size,
                              hipStream_t stream) {
    const void* x       = d_in[0];
    const void* weights = d_in[1];
    const void* indices = d_in[2];
    float*      out     = (float*)d_out;

    float4*       coeffs = (float4*)((char*)d_ws + 256);
    unsigned int* x_Tb   = (unsigned int*)((char*)d_ws + 2u * 1024u * 1024u);

    const size_t need = 2u * 1024u * 1024u +
                        (size_t)IN_DIM * (BATCH / 2) * sizeof(unsigned int); // ~34 MiB

    if (ws_size >= need) {
        // Co-residency for the custom barrier WITHOUT cooperative launch:
        // grid = 1024 (4 blocks/CU) vs true capacity 8/CU -> 2x slack.
        static int s_nb = 0;
        if (s_nb == 0) {
            int maxPerCU = 0;
            if (hipOccupancyMaxActiveBlocksPerMultiprocessor(
                    &maxPerCU, reinterpret_cast<const void*>(fused_kernel),
                    256, 0) != hipSuccess || maxPerCU < 1) {
                maxPerCU = 4;  // conservative floor (true capacity is 8)
            }
            int nb = (maxPerCU >= 4) ? 1024 : maxPerCU * 256;
            s_nb = nb;
        }
        int nb = s_nb;

        fused_kernel<<<dim3(nb), dim3(256), 0, stream>>>(
            x, weights, indices, x_Tb, coeffs, out, nb);
    } else {
        prep_kernel<<<dim3(COEFF_BLOCKS), dim3(256), 0, stream>>>(
            x, weights, x_Tb, coeffs, /*trans_blocks=*/0);
        dim3 grid(OUT_DIM / 256, BATCH / 32);
        logic_direct_kernel<<<grid, dim3(256), 0, stream>>>(
            x, indices, coeffs, out);
    }
}

// Round 8
// 137.573 us; speedup vs baseline: 2.7880x; 2.3949x over previous
//
#include <hip/hip_runtime.h>

#define IN_DIM  65536
#define OUT_DIM 65536
#define BATCH   256

// ws layout: float4 coeffs[OUT_DIM] @256 ; uint x_Tb[IN_DIM * BATCH/2] @2MiB (packed bf16 pairs).

__device__ __forceinline__ float bf2f(unsigned short h) {
    return __uint_as_float(((unsigned int)h) << 16);
}
__device__ __forceinline__ unsigned short f2bf(float f) {
    unsigned int u = __float_as_uint(f);
    u += 0x7FFFu + ((u >> 16) & 1u);
    return (unsigned short)(u >> 16);
}

// Softmax over 16 logits collapsed to affine coeffs of out = w0 + w1*a + w2*b + w3*ab.
__device__ __forceinline__ float4 collapse16(const float* w) {
    float m = w[0];
    #pragma unroll
    for (int f = 1; f < 16; ++f) m = fmaxf(m, w[f]);
    float e[16]; float sum = 0.f;
    #pragma unroll
    for (int f = 0; f < 16; ++f) { e[f] = __expf(w[f] - m); sum += e[f]; }
    float inv = 1.0f / sum;
    float w0 = e[8] + e[9] + e[10] + e[11] + e[12] + e[13] + e[14] + e[15];
    float w1 = (e[2] + e[3] + e[6] + e[7]) - (e[8] + e[9] + e[12] + e[13]);
    float w2 = (e[4] + e[5] + e[6] + e[7]) - (e[8] + e[9] + e[10] + e[11]);
    float w3 = e[1] - e[2] - e[4] - 2.f*e[6] - e[7]
             + e[8] + 2.f*e[9] + e[11] + e[13] - e[14];
    return make_float4(w0 * inv, w1 * inv, w2 * inv, w3 * inv);
}

#define TRANS_BLOCKS ((IN_DIM / 64) * (BATCH / 64))   // 4096
#define COEFF_BLOCKS (OUT_DIM / 256)                  // 256
#define PAD 69   // 69 % 32 = 5 -> column-phase reads are <=2-way (free)

// ---------------------------------------------------------------------------
// R10: fusion abandoned (R4/R6/R7: resident-grid shape stuck at 245-450 us
// vs <83 us for the two kernels; coop overhead ~100 us was only part of it).
// Back to the proven two-kernel structure. This round's single variable:
// logic kernel = STAGED-TILE shape (32 neurons x full 256-batch per block,
// cooperative coalesced 512B row gathers into XOR-swizzled LDS, coalesced
// NT stores) vs R5's 1-neuron/thread divergent-gather shape.
//   R5 shape:  each wave-load touches ~64 lines; each x_Tb line fetched 2x
//              (half-line per y-block, different XCDs).
//   staged:    4 lines/wave-load, each row read exactly once, full lines.
// Correctness of the staged shape is already harness-proven (fused phase 2).
// ---------------------------------------------------------------------------

// Kernel A: fused transpose (x [BATCH,IN_DIM] -> packed-bf16 x_Tb
// [IN_DIM, BATCH/2 dwords]) + per-neuron softmax-collapse coeffs.
__global__ __launch_bounds__(256) void prep_kernel(
    const void* __restrict__ x_raw,       // [BATCH, IN_DIM] fp32 or bf16
    const void* __restrict__ w_raw,       // [OUT_DIM, 16]   fp32 or bf16
    unsigned int* __restrict__ x_Tb,      // [IN_DIM, BATCH/2] packed bf16
    float4* __restrict__ coeffs,          // [OUT_DIM]
    int trans_blocks)
{
    __shared__ float tile[64][PAD];       // [batch_row][col]
    __shared__ int sflag;
    int t  = threadIdx.x;
    int bx = blockIdx.x;

    if (bx < trans_blocks) {
        if (t == 0) sflag = 0;
        __syncthreads();
        if (((const unsigned short*)x_raw)[t] >= 0x3F80u) atomicOr(&sflag, 1);
        __syncthreads();
        int x_is_f32 = sflag;

        int c0 = (bx >> 2) * 64;   // input-dim tile
        int b0 = (bx & 3) * 64;    // batch tile
        int cq = t & 15;           // float4 col group (4 cols)
        int r  = t >> 4;           // 0..15

        if (x_is_f32) {
            const float4* x4 = (const float4*)x_raw;
            #pragma unroll
            for (int k = 0; k < 4; ++k) {
                int row = r + 16 * k;
                float4 v = x4[(size_t)(b0 + row) * (IN_DIM / 4) + (c0 >> 2) + cq];
                tile[row][4 * cq + 0] = v.x;
                tile[row][4 * cq + 1] = v.y;
                tile[row][4 * cq + 2] = v.z;
                tile[row][4 * cq + 3] = v.w;
            }
        } else {
            const uint2* x2 = (const uint2*)x_raw;  // 4 bf16 per uint2
            #pragma unroll
            for (int k = 0; k < 4; ++k) {
                int row = r + 16 * k;
                uint2 v = x2[(size_t)(b0 + row) * (IN_DIM / 4) + (c0 >> 2) + cq];
                tile[row][4 * cq + 0] = bf2f((unsigned short)(v.x & 0xFFFFu));
                tile[row][4 * cq + 1] = bf2f((unsigned short)(v.x >> 16));
                tile[row][4 * cq + 2] = bf2f((unsigned short)(v.y & 0xFFFFu));
                tile[row][4 * cq + 3] = bf2f((unsigned short)(v.y >> 16));
            }
        }
        __syncthreads();

        // pack columns: per col, 32 dwords (64 batch) = 8 uint4; 512 uint4/tile
        uint4* dst = (uint4*)x_Tb;
        int q   = t & 7;          // uint4 index within col (batch 8q..8q+7)
        int col = t >> 3;         // 0..31, second iter +32
        #pragma unroll
        for (int it = 0; it < 2; ++it) {
            int cc = col + 32 * it;
            unsigned int d[4];
            #pragma unroll
            for (int j = 0; j < 4; ++j) {
                float lo = tile[8 * q + 2 * j][cc];
                float hi = tile[8 * q + 2 * j + 1][cc];
                d[j] = (unsigned int)f2bf(lo) | ((unsigned int)f2bf(hi) << 16);
            }
            dst[(size_t)(c0 + cc) * (BATCH / 8) + (b0 >> 3) + q] =
                make_uint4(d[0], d[1], d[2], d[3]);
        }
    } else {
        // ---- coeff block ----
        if (t == 0) sflag = 0;
        __syncthreads();
        if ((((const unsigned short*)w_raw)[t] & 0x7FFFu) >= 0x4800u) atomicOr(&sflag, 1);
        __syncthreads();
        int w_is_f32 = sflag;

        int o = (bx - trans_blocks) * 256 + t;
        if (o >= OUT_DIM) return;

        float w[16];
        if (w_is_f32) {
            const float4* w4 = reinterpret_cast<const float4*>(w_raw) + (size_t)o * 4;
            float4 q0 = w4[0], q1 = w4[1], q2 = w4[2], q3 = w4[3];
            w[0]=q0.x; w[1]=q0.y; w[2]=q0.z; w[3]=q0.w;
            w[4]=q1.x; w[5]=q1.y; w[6]=q1.z; w[7]=q1.w;
            w[8]=q2.x; w[9]=q2.y; w[10]=q2.z; w[11]=q2.w;
            w[12]=q3.x; w[13]=q3.y; w[14]=q3.z; w[15]=q3.w;
        } else {
            const uint4* w16 = reinterpret_cast<const uint4*>(
                (const unsigned short*)w_raw + (size_t)o * 16);
            uint4 p0 = w16[0], p1 = w16[1];
            unsigned int pk[8] = { p0.x, p0.y, p0.z, p0.w, p1.x, p1.y, p1.z, p1.w };
            #pragma unroll
            for (int i = 0; i < 8; ++i) {
                w[2*i]   = bf2f((unsigned short)(pk[i] & 0xFFFFu));
                w[2*i+1] = bf2f((unsigned short)(pk[i] >> 16));
            }
        }
        coeffs[o] = collapse16(w);
    }
}

// ---------------------------------------------------------------------------
// Kernel B (staged-tile shape): block owns 32 neurons x full 256-batch.
// 64 operand rows (512B each) gathered COALESCED (32 lanes x 16B per row,
// each row touched exactly once, 4 full lines) into 32KiB XOR-swizzled LDS
// (phys_quad = l ^ (row&31) -> ds_read conflict-free). Compute reads pairs,
// applies affine combine, stores NT with consecutive lanes on consecutive
// neurons (full 128B segments).
// ---------------------------------------------------------------------------
__global__ __launch_bounds__(256) void logic_bt_kernel(
    const unsigned int* __restrict__ x_Tb,  // [IN_DIM, BATCH/2]
    const void* __restrict__ idx_raw,       // [2, OUT_DIM] int32 or int64
    const float4* __restrict__ coeffs,
    float* __restrict__ out)                // [BATCH, OUT_DIM]
{
    __shared__ uint4 rows4[64 * 32];        // 32 KiB
    __shared__ int sflag;
    int t = threadIdx.x;
    if (t == 0) sflag = 0;
    __syncthreads();
    if ((t & 1) && ((const int*)idx_raw)[t] != 0) atomicOr(&sflag, 1);
    __syncthreads();
    int idx_is_i32 = sflag;   // odd dwords nonzero -> int32

    int o0 = blockIdx.x * 32;
    int rr = t >> 5;          // 0..7: row within pass
    int l  = t & 31;          // uint4 slot within row
    int wires[8];
    if (idx_is_i32) {
        const int* p = (const int*)idx_raw;
        #pragma unroll
        for (int ps = 0; ps < 8; ++ps) {
            int r = rr + 8 * ps;                 // 0..63
            wires[ps] = p[(r >> 5) * OUT_DIM + o0 + (r & 31)];
        }
    } else {
        const long long* p = (const long long*)idx_raw;
        #pragma unroll
        for (int ps = 0; ps < 8; ++ps) {
            int r = rr + 8 * ps;
            wires[ps] = (int)p[(r >> 5) * OUT_DIM + o0 + (r & 31)];
        }
    }

    const uint4* src4 = (const uint4*)x_Tb;
    #pragma unroll
    for (int ps = 0; ps < 8; ++ps) {
        int r = rr + 8 * ps;
        rows4[r * 32 + (l ^ (r & 31))] = src4[((size_t)wires[ps] << 5) + l];
    }
    float4 c = coeffs[o0 + (t & 31)];   // issued before the barrier
    __syncthreads();

    int o = t & 31;                     // neuron within block (== swizzle key)
    const uint4* ra4 = rows4 + o * 32;
    const uint4* rb4 = rows4 + (32 + o) * 32;
    float* outp = out + o0 + o;
    #pragma unroll
    for (int i = 0; i < 4; ++i) {
        int bq = (t >> 5) + 8 * i;      // batch quad 0..31 (batch 8bq..8bq+7)
        uint4 ua = ra4[bq ^ o];
        uint4 ub = rb4[bq ^ o];
        unsigned int pa[4] = { ua.x, ua.y, ua.z, ua.w };
        unsigned int pb[4] = { ub.x, ub.y, ub.z, ub.w };
        int base = bq * 8;
        #pragma unroll
        for (int j = 0; j < 4; ++j) {
            float a0 = bf2f((unsigned short)(pa[j] & 0xFFFFu));
            float a1 = bf2f((unsigned short)(pa[j] >> 16));
            float v0 = bf2f((unsigned short)(pb[j] & 0xFFFFu));
            float v1 = bf2f((unsigned short)(pb[j] >> 16));
            float r0v = fmaf(v0, fmaf(c.w, a0, c.z), fmaf(c.y, a0, c.x));
            float r1v = fmaf(v1, fmaf(c.w, a1, c.z), fmaf(c.y, a1, c.x));
            __builtin_nontemporal_store(r0v, outp + (size_t)(base + 2*j)     * OUT_DIM);
            __builtin_nontemporal_store(r1v, outp + (size_t)(base + 2*j + 1) * OUT_DIM);
        }
    }
}

// ---------------------------------------------------------------------------
// Fallback: direct gather from row-major x (only if ws can't hold x_Tb).
// ---------------------------------------------------------------------------
__global__ __launch_bounds__(256) void logic_direct_kernel(
    const void* __restrict__ x_raw,
    const void* __restrict__ idx_raw,
    const float4* __restrict__ coeffs,
    float* __restrict__ out)
{
    __shared__ int sflag;
    int t = threadIdx.x;
    if (t == 0) sflag = 0;
    __syncthreads();
    int fl = 0;
    if (((const unsigned short*)x_raw)[t] >= 0x3F80u) fl |= 1;
    if ((t & 1) && ((const int*)idx_raw)[t] != 0) fl |= 2;
    if (fl) atomicOr(&sflag, fl);
    __syncthreads();
    int x_is_f32   = sflag & 1;
    int idx_is_i32 = (sflag >> 1) & 1;

    int o = blockIdx.x * 256 + t;
    int ia, ib;
    if (idx_is_i32) {
        const int* p = (const int*)idx_raw;
        ia = p[o];       ib = p[OUT_DIM + o];
    } else {
        const long long* p = (const long long*)idx_raw;
        ia = (int)p[o];  ib = (int)p[OUT_DIM + o];
    }
    float4 c = coeffs[o];
    int b0 = blockIdx.y * 32;

    if (x_is_f32) {
        const float* xa = (const float*)x_raw + ia;
        const float* xb = (const float*)x_raw + ib;
        #pragma unroll 8
        for (int r = 0; r < 32; ++r) {
            int b = b0 + r;
            float av = xa[(size_t)b * IN_DIM];
            float bv = xb[(size_t)b * IN_DIM];
            out[(size_t)b * OUT_DIM + o] =
                fmaf(bv, fmaf(c.w, av, c.z), fmaf(c.y, av, c.x));
        }
    } else {
        const unsigned short* xa = (const unsigned short*)x_raw + ia;
        const unsigned short* xb = (const unsigned short*)x_raw + ib;
        #pragma unroll 8
        for (int r = 0; r < 32; ++r) {
            int b = b0 + r;
            float av = bf2f(xa[(size_t)b * IN_DIM]);
            float bv = bf2f(xb[(size_t)b * IN_DIM]);
            out[(size_t)b * OUT_DIM + o] =
                fmaf(bv, fmaf(c.w, av, c.z), fmaf(c.y, av, c.x));
        }
    }
}

extern "C" void kernel_launch(void* const* d_in, const int* in_sizes, int n_in,
                              void* d_out, int out_size, void* d_ws, size_t ws_size,
                              hipStream_t stream) {
    const void* x       = d_in[0];
    const void* weights = d_in[1];
    const void* indices = d_in[2];
    float*      out     = (float*)d_out;

    float4*       coeffs = (float4*)((char*)d_ws + 256);
    unsigned int* x_Tb   = (unsigned int*)((char*)d_ws + 2u * 1024u * 1024u);

    const size_t need = 2u * 1024u * 1024u +
                        (size_t)IN_DIM * (BATCH / 2) * sizeof(unsigned int); // ~34 MiB

    if (ws_size >= need) {
        prep_kernel<<<dim3(TRANS_BLOCKS + COEFF_BLOCKS), dim3(256), 0, stream>>>(
            x, weights, x_Tb, coeffs, TRANS_BLOCKS);
        logic_bt_kernel<<<dim3(OUT_DIM / 32), dim3(256), 0, stream>>>(
            x_Tb, indices, coeffs, out);
    } else {
        prep_kernel<<<dim3(COEFF_BLOCKS), dim3(256), 0, stream>>>(
            x, weights, x_Tb, coeffs, /*trans_blocks=*/0);
        dim3 grid(OUT_DIM / 256, BATCH / 32);
        logic_direct_kernel<<<grid, dim3(256), 0, stream>>>(
            x, indices, coeffs, out);
    }
}

// Round 10
// 135.287 us; speedup vs baseline: 2.8352x; 1.0169x over previous
//
#include <hip/hip_runtime.h>

#define IN_DIM  65536
#define OUT_DIM 65536
#define BATCH   256

// ws layout: float4 coeffs[OUT_DIM] @256 ; uint x_Tb[IN_DIM * BATCH/2] @2MiB (packed bf16 pairs).

__device__ __forceinline__ float bf2f(unsigned short h) {
    return __uint_as_float(((unsigned int)h) << 16);
}
__device__ __forceinline__ unsigned short f2bf(float f) {
    unsigned int u = __float_as_uint(f);
    u += 0x7FFFu + ((u >> 16) & 1u);
    return (unsigned short)(u >> 16);
}

// Softmax over 16 logits collapsed to affine coeffs of out = w0 + w1*a + w2*b + w3*ab.
__device__ __forceinline__ float4 collapse16(const float* w) {
    float m = w[0];
    #pragma unroll
    for (int f = 1; f < 16; ++f) m = fmaxf(m, w[f]);
    float e[16]; float sum = 0.f;
    #pragma unroll
    for (int f = 0; f < 16; ++f) { e[f] = __expf(w[f] - m); sum += e[f]; }
    float inv = 1.0f / sum;
    float w0 = e[8] + e[9] + e[10] + e[11] + e[12] + e[13] + e[14] + e[15];
    float w1 = (e[2] + e[3] + e[6] + e[7]) - (e[8] + e[9] + e[12] + e[13]);
    float w2 = (e[4] + e[5] + e[6] + e[7]) - (e[8] + e[9] + e[10] + e[11]);
    float w3 = e[1] - e[2] - e[4] - 2.f*e[6] - e[7]
             + e[8] + 2.f*e[9] + e[11] + e[13] - e[14];
    return make_float4(w0 * inv, w1 * inv, w2 * inv, w3 * inv);
}

#define TRANS_BLOCKS ((IN_DIM / 64) * (BATCH / 64))   // 4096
#define COEFF_BLOCKS (OUT_DIM / 256)                  // 256
#define PAD 69   // 69 % 32 = 5 -> column-phase reads are <=2-way (free)

// ---------------------------------------------------------------------------
// R11 (resubmitted): two-kernel structure (R8 = 137.6 us). Single variable:
// logic kernel fulltile (32 KiB LDS, 5 blocks/CU) -> HALFTILE
// (32 neurons x 128-batch, 16 KiB LDS, 8 blocks/CU, grid 4096).
// Same total gather bytes (64 MB, full 128B lines), same coalesced NT out
// stores; 1.6x more resident waves to hide the ~500cy random L3 gather
// latency. Staging is explicit load-all-then-write-all for max MLP.
// ---------------------------------------------------------------------------

// Kernel A: fused transpose (x [BATCH,IN_DIM] -> packed-bf16 x_Tb) + coeffs.
__global__ __launch_bounds__(256) void prep_kernel(
    const void* __restrict__ x_raw,       // [BATCH, IN_DIM] fp32 or bf16
    const void* __restrict__ w_raw,       // [OUT_DIM, 16]   fp32 or bf16
    unsigned int* __restrict__ x_Tb,      // [IN_DIM, BATCH/2] packed bf16
    float4* __restrict__ coeffs,          // [OUT_DIM]
    int trans_blocks)
{
    __shared__ float tile[64][PAD];       // [batch_row][col]
    __shared__ int sflag;
    int t  = threadIdx.x;
    int bx = blockIdx.x;

    if (bx < trans_blocks) {
        if (t == 0) sflag = 0;
        __syncthreads();
        if (((const unsigned short*)x_raw)[t] >= 0x3F80u) atomicOr(&sflag, 1);
        __syncthreads();
        int x_is_f32 = sflag;

        int c0 = (bx >> 2) * 64;   // input-dim tile
        int b0 = (bx & 3) * 64;    // batch tile
        int cq = t & 15;           // float4 col group (4 cols)
        int r  = t >> 4;           // 0..15

        if (x_is_f32) {
            const float4* x4 = (const float4*)x_raw;
            #pragma unroll
            for (int k = 0; k < 4; ++k) {
                int row = r + 16 * k;
                float4 v = x4[(size_t)(b0 + row) * (IN_DIM / 4) + (c0 >> 2) + cq];
                tile[row][4 * cq + 0] = v.x;
                tile[row][4 * cq + 1] = v.y;
                tile[row][4 * cq + 2] = v.z;
                tile[row][4 * cq + 3] = v.w;
            }
        } else {
            const uint2* x2 = (const uint2*)x_raw;  // 4 bf16 per uint2
            #pragma unroll
            for (int k = 0; k < 4; ++k) {
                int row = r + 16 * k;
                uint2 v = x2[(size_t)(b0 + row) * (IN_DIM / 4) + (c0 >> 2) + cq];
                tile[row][4 * cq + 0] = bf2f((unsigned short)(v.x & 0xFFFFu));
                tile[row][4 * cq + 1] = bf2f((unsigned short)(v.x >> 16));
                tile[row][4 * cq + 2] = bf2f((unsigned short)(v.y & 0xFFFFu));
                tile[row][4 * cq + 3] = bf2f((unsigned short)(v.y >> 16));
            }
        }
        __syncthreads();

        // pack columns: per col, 32 dwords (64 batch) = 8 uint4; 512 uint4/tile
        uint4* dst = (uint4*)x_Tb;
        int q   = t & 7;          // uint4 index within col (batch 8q..8q+7)
        int col = t >> 3;         // 0..31, second iter +32
        #pragma unroll
        for (int it = 0; it < 2; ++it) {
            int cc = col + 32 * it;
            unsigned int d[4];
            #pragma unroll
            for (int j = 0; j < 4; ++j) {
                float lo = tile[8 * q + 2 * j][cc];
                float hi = tile[8 * q + 2 * j + 1][cc];
                d[j] = (unsigned int)f2bf(lo) | ((unsigned int)f2bf(hi) << 16);
            }
            dst[(size_t)(c0 + cc) * (BATCH / 8) + (b0 >> 3) + q] =
                make_uint4(d[0], d[1], d[2], d[3]);
        }
    } else {
        // ---- coeff block ----
        if (t == 0) sflag = 0;
        __syncthreads();
        if ((((const unsigned short*)w_raw)[t] & 0x7FFFu) >= 0x4800u) atomicOr(&sflag, 1);
        __syncthreads();
        int w_is_f32 = sflag;

        int o = (bx - trans_blocks) * 256 + t;
        if (o >= OUT_DIM) return;

        float w[16];
        if (w_is_f32) {
            const float4* w4 = reinterpret_cast<const float4*>(w_raw) + (size_t)o * 4;
            float4 q0 = w4[0], q1 = w4[1], q2 = w4[2], q3 = w4[3];
            w[0]=q0.x; w[1]=q0.y; w[2]=q0.z; w[3]=q0.w;
            w[4]=q1.x; w[5]=q1.y; w[6]=q1.z; w[7]=q1.w;
            w[8]=q2.x; w[9]=q2.y; w[10]=q2.z; w[11]=q2.w;
            w[12]=q3.x; w[13]=q3.y; w[14]=q3.z; w[15]=q3.w;
        } else {
            const uint4* w16 = reinterpret_cast<const uint4*>(
                (const unsigned short*)w_raw + (size_t)o * 16);
            uint4 p0 = w16[0], p1 = w16[1];
            unsigned int pk[8] = { p0.x, p0.y, p0.z, p0.w, p1.x, p1.y, p1.z, p1.w };
            #pragma unroll
            for (int i = 0; i < 8; ++i) {
                w[2*i]   = bf2f((unsigned short)(pk[i] & 0xFFFFu));
                w[2*i+1] = bf2f((unsigned short)(pk[i] >> 16));
            }
        }
        coeffs[o] = collapse16(w);
    }
}

// ---------------------------------------------------------------------------
// Kernel B (halftile): block owns 32 neurons x 128-batch half.
// 64 rows x 256B gathered coalesced (16 lanes x 16B per row, full 128B
// lines, each half-row touched once) into 16 KiB XOR-swizzled LDS
// (phys = l ^ (r&15)). 8 blocks/CU. Coalesced NT stores.
// ---------------------------------------------------------------------------
__global__ __launch_bounds__(256, 8) void logic_bt_kernel(
    const unsigned int* __restrict__ x_Tb,  // [IN_DIM, BATCH/2]
    const void* __restrict__ idx_raw,       // [2, OUT_DIM] int32 or int64
    const float4* __restrict__ coeffs,
    float* __restrict__ out)                // [BATCH, OUT_DIM]
{
    __shared__ uint4 rows4[64 * 16];        // 16 KiB
    __shared__ int sflag;
    int t = threadIdx.x;
    if (t == 0) sflag = 0;
    __syncthreads();
    if ((t & 1) && ((const int*)idx_raw)[t] != 0) atomicOr(&sflag, 1);
    __syncthreads();
    int idx_is_i32 = sflag;   // odd dwords nonzero -> int32

    int lt = blockIdx.x;
    int o0 = (lt >> 1) * 32;
    int hc = (lt & 1) * 16;   // uint4 col offset within full row
    int rr = t >> 4;          // 0..15: row within pass
    int l  = t & 15;          // uint4 slot within 256B half-row

    int wires[4];
    if (idx_is_i32) {
        const int* p = (const int*)idx_raw;
        #pragma unroll
        for (int ps = 0; ps < 4; ++ps) {
            int r = rr + 16 * ps;                // 0..63
            wires[ps] = p[(r >> 5) * OUT_DIM + o0 + (r & 31)];
        }
    } else {
        const long long* p = (const long long*)idx_raw;
        #pragma unroll
        for (int ps = 0; ps < 4; ++ps) {
            int r = rr + 16 * ps;
            wires[ps] = (int)p[(r >> 5) * OUT_DIM + o0 + (r & 31)];
        }
    }

    // load-all-then-write-all: 4 independent gathers in flight per thread
    const uint4* src4 = (const uint4*)x_Tb;
    uint4 v[4];
    #pragma unroll
    for (int ps = 0; ps < 4; ++ps)
        v[ps] = src4[(size_t)wires[ps] * (BATCH / 8) + hc + l];
    float4 c = coeffs[o0 + (t & 31)];
    #pragma unroll
    for (int ps = 0; ps < 4; ++ps) {
        int r = rr + 16 * ps;
        rows4[r * 16 + (l ^ (r & 15))] = v[ps];
    }
    __syncthreads();

    int o = t & 31;           // neuron within tile
    const uint4* ra4 = rows4 + o * 16;
    const uint4* rb4 = rows4 + (32 + o) * 16;
    float* outp = out + o0 + o;
    int B0 = (lt & 1) * 128;
    #pragma unroll
    for (int i = 0; i < 2; ++i) {
        int bq = (t >> 5) + 8 * i;      // batch quad within half: 0..15
        uint4 ua = ra4[bq ^ (o & 15)];
        uint4 ub = rb4[bq ^ (o & 15)];
        unsigned int pa[4] = { ua.x, ua.y, ua.z, ua.w };
        unsigned int pb[4] = { ub.x, ub.y, ub.z, ub.w };
        int base = B0 + bq * 8;
        #pragma unroll
        for (int j = 0; j < 4; ++j) {
            float a0 = bf2f((unsigned short)(pa[j] & 0xFFFFu));
            float a1 = bf2f((unsigned short)(pa[j] >> 16));
            float v0 = bf2f((unsigned short)(pb[j] & 0xFFFFu));
            float v1 = bf2f((unsigned short)(pb[j] >> 16));
            float r0v = fmaf(v0, fmaf(c.w, a0, c.z), fmaf(c.y, a0, c.x));
            float r1v = fmaf(v1, fmaf(c.w, a1, c.z), fmaf(c.y, a1, c.x));
            __builtin_nontemporal_store(r0v, outp + (size_t)(base + 2*j)     * OUT_DIM);
            __builtin_nontemporal_store(r1v, outp + (size_t)(base + 2*j + 1) * OUT_DIM);
        }
    }
}

// ---------------------------------------------------------------------------
// Fallback: direct gather from row-major x (only if ws can't hold x_Tb).
// ---------------------------------------------------------------------------
__global__ __launch_bounds__(256) void logic_direct_kernel(
    const void* __restrict__ x_raw,
    const void* __restrict__ idx_raw,
    const float4* __restrict__ coeffs,
    float* __restrict__ out)
{
    __shared__ int sflag;
    int t = threadIdx.x;
    if (t == 0) sflag = 0;
    __syncthreads();
    int fl = 0;
    if (((const unsigned short*)x_raw)[t] >= 0x3F80u) fl |= 1;
    if ((t & 1) && ((const int*)idx_raw)[t] != 0) fl |= 2;
    if (fl) atomicOr(&sflag, fl);
    __syncthreads();
    int x_is_f32   = sflag & 1;
    int idx_is_i32 = (sflag >> 1) & 1;

    int o = blockIdx.x * 256 + t;
    int ia, ib;
    if (idx_is_i32) {
        const int* p = (const int*)idx_raw;
        ia = p[o];       ib = p[OUT_DIM + o];
    } else {
        const long long* p = (const long long*)idx_raw;
        ia = (int)p[o];  ib = (int)p[OUT_DIM + o];
    }
    float4 c = coeffs[o];
    int b0 = blockIdx.y * 32;

    if (x_is_f32) {
        const float* xa = (const float*)x_raw + ia;
        const float* xb = (const float*)x_raw + ib;
        #pragma unroll 8
        for (int r = 0; r < 32; ++r) {
            int b = b0 + r;
            float av = xa[(size_t)b * IN_DIM];
            float bv = xb[(size_t)b * IN_DIM];
            out[(size_t)b * OUT_DIM + o] =
                fmaf(bv, fmaf(c.w, av, c.z), fmaf(c.y, av, c.x));
        }
    } else {
        const unsigned short* xa = (const unsigned short*)x_raw + ia;
        const unsigned short* xb = (const unsigned short*)x_raw + ib;
        #pragma unroll 8
        for (int r = 0; r < 32; ++r) {
            int b = b0 + r;
            float av = bf2f(xa[(size_t)b * IN_DIM]);
            float bv = bf2f(xb[(size_t)b * IN_DIM]);
            out[(size_t)b * OUT_DIM + o] =
                fmaf(bv, fmaf(c.w, av, c.z), fmaf(c.y, av, c.x));
        }
    }
}

extern "C" void kernel_launch(void* const* d_in, const int* in_sizes, int n_in,
                              void* d_out, int out_size, void* d_ws, size_t ws_size,
                              hipStream_t stream) {
    const void* x       = d_in[0];
    const void* weights = d_in[1];
    const void* indices = d_in[2];
    float*      out     = (float*)d_out;

    float4*       coeffs = (float4*)((char*)d_ws + 256);
    unsigned int* x_Tb   = (unsigned int*)((char*)d_ws + 2u * 1024u * 1024u);

    const size_t need = 2u * 1024u * 1024u +
                        (size_t)IN_DIM * (BATCH / 2) * sizeof(unsigned int); // ~34 MiB

    if (ws_size >= need) {
        prep_kernel<<<dim3(TRANS_BLOCKS + COEFF_BLOCKS), dim3(256), 0, stream>>>(
            x, weights, x_Tb, coeffs, TRANS_BLOCKS);
        logic_bt_kernel<<<dim3((OUT_DIM / 32) * 2), dim3(256), 0, stream>>>(
            x_Tb, indices, coeffs, out);
    } else {
        prep_kernel<<<dim3(COEFF_BLOCKS), dim3(256), 0, stream>>>(
            x, weights, x_Tb, coeffs, /*trans_blocks=*/0);
        dim3 grid(OUT_DIM / 256, BATCH / 32);
        logic_direct_kernel<<<grid, dim3(256), 0, stream>>>(
            x, indices, coeffs, out);
    }
}